// Round 5
// baseline (1405.887 us; speedup 1.0000x reference)
//
#include <hip/hip_runtime.h>
#include <hip/hip_bf16.h>

// GRU: BATCH=256, SEQ=512, INPUT=128, HIDDEN=256, fp32 in/out.
// Phase 0 (gru_wprep): one-shot gather of X-part weight frags into a 192 KB table.
// Phase 1 (gru_xpre): Gx = X @ W_g[:,256:384].T + b_g (bf16, swizzled chunks).
//   4 WGs per timestep, gate-looped, occupancy 2.
// Phase 2 (gru_seq): persistent batch-split recurrence, 16 WGs x 512 thr.
//   ALL weight frags register-resident: Wz/Wr (128 regs) + Wc (64 regs); no wc_lds.
//   Phase-B LDS reads halved (was the dominant serialization). h/rh rows padded
//   to 260 shorts (130 dw == 2 mod 32) to break the 8-lane same-bank-window
//   classes on A-frag b128 reads (measured: exactly 4 conflict-cyc per A-read,
//   invariant across write-layout changes). Gx loads pipelined one step ahead;
//   lgkm-only barriers keep Gx loads / out stores in flight across them.
// Fallback (gru_fallback): naive fp32, used only if ws too small.

typedef float f32x4 __attribute__((ext_vector_type(4)));
typedef short s16x8 __attribute__((ext_vector_type(8)));

#define SEQ 512
#define NB  256
#define NI  128
#define NH  256
#define WROW 384               // W leading dim (H+I)
#define HPAD 260               // h/rh row pitch in shorts (130 dw == 2 mod 32)
#define GX_BYTES ((size_t)201326592)   // 512 t * 768 chunks * 512 B
#define WTAB_BYTES ((size_t)196608)    // 192 frags * 64 lanes * 16 B

static __device__ inline float bf2f(unsigned short s) {
    unsigned u = ((unsigned)s) << 16;
    return __builtin_bit_cast(float, u);
}
// packed f32x2 -> bf16x2 (RTNE) via v_cvt_pk_bf16_f32
static __device__ inline unsigned pkbf(float a, float b) {
    __hip_bfloat162 h = __float22bfloat162_rn(make_float2(a, b));
    unsigned r;
    __builtin_memcpy(&r, &h, 4);
    return r;
}
static __device__ inline s16x8 pk8(f32x4 f0, f32x4 f1) {
    uint4 u;
    u.x = pkbf(f0[0], f0[1]);
    u.y = pkbf(f0[2], f0[3]);
    u.z = pkbf(f1[0], f1[1]);
    u.w = pkbf(f1[2], f1[3]);
    return __builtin_bit_cast(s16x8, u);
}
static __device__ inline float fexp2(float x) {
#if __has_builtin(__builtin_amdgcn_exp2f)
    return __builtin_amdgcn_exp2f(x);
#else
    return exp2f(x);
#endif
}
static __device__ inline float frcp(float x) {
#if __has_builtin(__builtin_amdgcn_rcpf)
    return __builtin_amdgcn_rcpf(x);
#else
    return 1.0f / x;
#endif
}
static __device__ inline float sigm(float x)  { return frcp(1.0f + fexp2(-1.44269504f * x)); }
static __device__ inline float tanh_(float x) { return 1.0f - 2.0f * frcp(1.0f + fexp2(2.88539008f * x)); }

// lgkm-only barrier: LDS visibility without draining vmem (loads/stores stay in flight)
static __device__ inline void lds_barrier() {
    asm volatile("s_waitcnt lgkmcnt(0)\n\ts_barrier" ::: "memory");
}

// ---------------------------------------------------------------------------
// Phase 0: one-shot W-frag table build. 48 WGs x 256 thr -> 12288 tasks.
// ---------------------------------------------------------------------------
__global__ __launch_bounds__(256, 1) void gru_wprep(
    const float* __restrict__ Wz, const float* __restrict__ Wr, const float* __restrict__ Wc,
    unsigned short* __restrict__ wtab)
{
    int task = blockIdx.x * 256 + threadIdx.x;
    int l  = task & 63;
    int fr = task >> 6;            // 0..191
    int v  = fr / 48;
    int f  = fr - v * 48;          // g*16 + tt*4 + kt
    int g  = f >> 4, tt = (f >> 2) & 3, kt = f & 3;
    const float* Wp = (g == 0) ? Wz : (g == 1) ? Wr : Wc;
    int j = v * 64 + tt * 16 + (l & 15);
    const float* src = Wp + (size_t)j * WROW + 256 + kt * 32 + (l >> 4) * 8;
    f32x4 f0 = *(const f32x4*)src;
    f32x4 f1 = *(const f32x4*)(src + 4);
    *(s16x8*)(wtab + (size_t)task * 8) = pk8(f0, f1);
}

// ---------------------------------------------------------------------------
// Phase 1: input projections. 4 WGs per timestep t (mq = batch quarter).
// ---------------------------------------------------------------------------
__global__ __launch_bounds__(256, 2) void gru_xpre(
    const float* __restrict__ X,
    const float* __restrict__ bz, const float* __restrict__ br, const float* __restrict__ bc,
    const unsigned short* __restrict__ wtab,
    unsigned short* __restrict__ Gx)
{
    __shared__ __align__(16) unsigned short x_lds[8192];   // 64 rows x 128 bf16, swizzled
    const int tid  = threadIdx.x;
    const int t    = blockIdx.x >> 2;
    const int mq   = blockIdx.x & 3;
    const int l    = tid & 63;
    const int v    = tid >> 6;
    const int quad = l >> 4;
    const int n    = l & 15;

    for (int i = tid; i < 1024; i += 256) {
        int lr = i >> 4, c = i & 15;
        const float* src = X + (size_t)((mq * 64 + lr) * SEQ + t) * NI + c * 8;
        f32x4 f0 = *(const f32x4*)(src);
        f32x4 f1 = *(const f32x4*)(src + 4);
        *(s16x8*)(&x_lds[lr * 128 + ((c ^ (lr & 15)) << 3)]) = pk8(f0, f1);
    }
    __syncthreads();

    const float* bp[3] = {bz, br, bc};
    const int rowA = n;
#pragma unroll 1
    for (int g = 0; g < 3; ++g) {
        s16x8 Bf[4][4];
        float bias[4];
#pragma unroll
        for (int tt = 0; tt < 4; ++tt) {
            bias[tt] = bp[g][v * 64 + tt * 16 + n];
#pragma unroll
            for (int kt = 0; kt < 4; ++kt)
                Bf[tt][kt] = *(const s16x8*)(wtab
                    + ((size_t)(v * 48 + g * 16 + tt * 4 + kt) * 64 + l) * 8);
        }

#pragma unroll 1
        for (int mtl = 0; mtl < 4; ++mtl) {
            const int mt = mq * 4 + mtl;
            f32x4 acc[4];
            const f32x4 z4 = {0.f, 0.f, 0.f, 0.f};
#pragma unroll
            for (int tt = 0; tt < 4; ++tt) acc[tt] = z4;

#pragma unroll
            for (int kt = 0; kt < 4; ++kt) {
                s16x8 a = *(const s16x8*)(&x_lds[(mtl * 16 + rowA) * 128
                                                 + (((kt * 4 + quad) ^ rowA) << 3)]);
#pragma unroll
                for (int tt = 0; tt < 4; ++tt)
                    acc[tt] = __builtin_amdgcn_mfma_f32_16x16x32_bf16(a, Bf[tt][kt], acc[tt], 0, 0, 0);
            }

#pragma unroll
            for (int tt = 0; tt < 4; ++tt) {
                float b = bias[tt];
                uint2 d;
                d.x = pkbf(acc[tt][0] + b, acc[tt][1] + b);
                d.y = pkbf(acc[tt][2] + b, acc[tt][3] + b);
                int chunk = (((t * 16 + mt) * 4 + v) * 3 + g) * 4 + tt;
                *(uint2*)((char*)Gx + (size_t)chunk * 512 + l * 8) = d;
            }
        }
    }
}

// ---------------------------------------------------------------------------
// Phase 1 (legacy gather variant, used when ws has room for Gx but not wtab)
// ---------------------------------------------------------------------------
__global__ __launch_bounds__(256, 1) void gru_xpre_gather(
    const float* __restrict__ X,
    const float* __restrict__ Wz, const float* __restrict__ bz,
    const float* __restrict__ Wr, const float* __restrict__ br,
    const float* __restrict__ Wc, const float* __restrict__ bc,
    unsigned short* __restrict__ Gx)
{
    __shared__ __align__(16) unsigned short x_lds[32768];
    const int tid  = threadIdx.x;
    const int t    = blockIdx.x;
    const int l    = tid & 63;
    const int v    = tid >> 6;
    const int quad = l >> 4;
    const int n    = l & 15;

    for (int i = tid; i < 4096; i += 256) {
        int row = i >> 4, c = i & 15;
        const float* src = X + (size_t)(row * SEQ + t) * NI + c * 8;
        f32x4 f0 = *(const f32x4*)(src);
        f32x4 f1 = *(const f32x4*)(src + 4);
        *(s16x8*)(&x_lds[row * 128 + ((c ^ (row & 15)) << 3)]) = pk8(f0, f1);
    }

    const float* Wp[3] = {Wz, Wr, Wc};
    const float* bp[3] = {bz, br, bc};
    s16x8 Bf[3][4][4];
    float bias[3][4];
#pragma unroll
    for (int g = 0; g < 3; ++g) {
#pragma unroll
        for (int tt = 0; tt < 4; ++tt) {
            int j = v * 64 + tt * 16 + n;
            bias[g][tt] = bp[g][j];
#pragma unroll
            for (int kt = 0; kt < 4; ++kt) {
                const float* src = Wp[g] + j * WROW + 256 + kt * 32 + quad * 8;
                f32x4 f0 = *(const f32x4*)(src);
                f32x4 f1 = *(const f32x4*)(src + 4);
                Bf[g][tt][kt] = pk8(f0, f1);
            }
        }
    }
    __syncthreads();

    const int rowA = l & 15;
#pragma unroll 1
    for (int mt = 0; mt < 16; ++mt) {
        f32x4 acc[3][4];
        f32x4 z4 = {0.f, 0.f, 0.f, 0.f};
#pragma unroll
        for (int g = 0; g < 3; ++g)
#pragma unroll
            for (int tt = 0; tt < 4; ++tt) acc[g][tt] = z4;

#pragma unroll
        for (int kt = 0; kt < 4; ++kt) {
            int row = mt * 16 + rowA;
            s16x8 a = *(const s16x8*)(&x_lds[row * 128 + (((kt * 4 + quad) ^ rowA) << 3)]);
#pragma unroll
            for (int g = 0; g < 3; ++g)
#pragma unroll
                for (int tt = 0; tt < 4; ++tt)
                    acc[g][tt] = __builtin_amdgcn_mfma_f32_16x16x32_bf16(a, Bf[g][tt][kt], acc[g][tt], 0, 0, 0);
        }

#pragma unroll
        for (int g = 0; g < 3; ++g)
#pragma unroll
            for (int tt = 0; tt < 4; ++tt) {
                float b = bias[g][tt];
                uint2 d;
                d.x = pkbf(acc[g][tt][0] + b, acc[g][tt][1] + b);
                d.y = pkbf(acc[g][tt][2] + b, acc[g][tt][3] + b);
                int chunk = (((t * 16 + mt) * 4 + v) * 3 + g) * 4 + tt;
                *(uint2*)((char*)Gx + (size_t)chunk * 512 + l * 8) = d;
            }
    }
}

// ---------------------------------------------------------------------------
// Phase 2: persistent recurrence. 16 WGs x 512 thr (8 waves, 2 waves/SIMD).
// Each wave handles j = w*32 .. w*32+31 (tt in [0,2)).
// ALL weight frags in registers: Wf (128 regs) + Wcr (64 regs). No wc_lds.
// LDS: 2 x 16 x 260 shorts = 16.6 KB. Gx loads pipelined one step ahead.
// ---------------------------------------------------------------------------
__global__ __launch_bounds__(512, 2) void gru_seq(
    const float* __restrict__ Wz, const float* __restrict__ Wr, const float* __restrict__ Wc,
    const unsigned short* __restrict__ Gx,
    float* __restrict__ out)
{
    __shared__ __align__(16) unsigned short h_lds[16][HPAD];
    __shared__ __align__(16) unsigned short rh_lds[16][HPAD];

    const int tid  = threadIdx.x;
    const int wg   = blockIdx.x;
    const int l    = tid & 63;
    const int w    = tid >> 6;       // wave 0..7
    const int quad = l >> 4;
    const int n    = l & 15;
    const int rowA = n;

    // resident Wz/Wr frags: Wf[g][tt][kt], j = w*32 + tt*16 + n, k = kt*32 + quad*8
    const float* Wp2[2] = {Wz, Wr};
    s16x8 Wf[2][2][8];
#pragma unroll
    for (int g = 0; g < 2; ++g)
#pragma unroll
        for (int tt = 0; tt < 2; ++tt)
#pragma unroll
            for (int kt = 0; kt < 8; ++kt) {
                int j = w * 32 + tt * 16 + n;
                const float* src = Wp2[g] + j * WROW + kt * 32 + quad * 8;
                f32x4 f0 = *(const f32x4*)(src);
                f32x4 f1 = *(const f32x4*)(src + 4);
                Wf[g][tt][kt] = pk8(f0, f1);
            }

    // resident Wc frags, all kt (same j/k mapping)
    s16x8 Wcr[2][8];
#pragma unroll
    for (int tt = 0; tt < 2; ++tt)
#pragma unroll
        for (int kt = 0; kt < 8; ++kt) {
            int j = w * 32 + tt * 16 + n;
            const float* src = Wc + j * WROW + kt * 32 + quad * 8;
            f32x4 f0 = *(const f32x4*)(src);
            f32x4 f1 = *(const f32x4*)(src + 4);
            Wcr[tt][kt] = pk8(f0, f1);
        }

    // zero h state
    {
        unsigned short* hz = &h_lds[0][0];
        for (int i = tid; i < 16 * HPAD; i += 512) hz[i] = 0;
    }
    float hreg[2][4];
#pragma unroll
    for (int tt = 0; tt < 2; ++tt)
#pragma unroll
        for (int r = 0; r < 4; ++r) hreg[tt][r] = 0.0f;
    __syncthreads();

    // Gx addressing: chunk = ((t*16+wg)*4 + (w>>1))*12 + g*4 + (w&1)*2 + tt
    const char* gxbase = (const char*)Gx
        + (size_t)(((wg * 4 + (w >> 1)) * 12 + (w & 1) * 2) * 512) + l * 8;
    float* outp = out + (size_t)(wg * 16 + quad * 4) * 256 + w * 32 + n;
    const f32x4 z4 = {0.f, 0.f, 0.f, 0.f};

    // preload Gx for t=0
    uint2 ga[6];
#pragma unroll
    for (int i = 0; i < 6; ++i)
        ga[i] = *(const uint2*)(gxbase + (i >> 1) * 2048 + (i & 1) * 512);

#pragma unroll 1
    for (int t = 0; t < SEQ; ++t) {
        const char* gbn = gxbase + (size_t)(t + 1 < SEQ ? t + 1 : t) * 393216;

        // z/r MFMA
        f32x4 accZ[2], accR[2];
#pragma unroll
        for (int tt = 0; tt < 2; ++tt) { accZ[tt] = z4; accR[tt] = z4; }
#pragma unroll
        for (int kt = 0; kt < 8; ++kt) {
            s16x8 a = *(const s16x8*)(&h_lds[rowA][kt * 32 + quad * 8]);
#pragma unroll
            for (int tt = 0; tt < 2; ++tt) {
                accZ[tt] = __builtin_amdgcn_mfma_f32_16x16x32_bf16(a, Wf[0][tt][kt], accZ[tt], 0, 0, 0);
                accR[tt] = __builtin_amdgcn_mfma_f32_16x16x32_bf16(a, Wf[1][tt][kt], accR[tt], 0, 0, 0);
            }
        }

        // epilogue 1: extract z/r Gx, reload ga[0..3] for t+1, compute z, r, write r*h
        float zs[2][4];
        {
            float gzf[2][4], grf[2][4];
#pragma unroll
            for (int tt = 0; tt < 2; ++tt) {
                uint2 gz = ga[tt], gr = ga[2 + tt];
                gzf[tt][0] = bf2f((unsigned short)(gz.x & 0xffffu));
                gzf[tt][1] = bf2f((unsigned short)(gz.x >> 16));
                gzf[tt][2] = bf2f((unsigned short)(gz.y & 0xffffu));
                gzf[tt][3] = bf2f((unsigned short)(gz.y >> 16));
                grf[tt][0] = bf2f((unsigned short)(gr.x & 0xffffu));
                grf[tt][1] = bf2f((unsigned short)(gr.x >> 16));
                grf[tt][2] = bf2f((unsigned short)(gr.y & 0xffffu));
                grf[tt][3] = bf2f((unsigned short)(gr.y >> 16));
            }
#pragma unroll
            for (int i = 0; i < 4; ++i)
                ga[i] = *(const uint2*)(gbn + (i >> 1) * 2048 + (i & 1) * 512);
#pragma unroll
            for (int tt = 0; tt < 2; ++tt) {
                float rh[4];
#pragma unroll
                for (int r = 0; r < 4; ++r) {
                    float zv = sigm(accZ[tt][r] + gzf[tt][r]);
                    float rv = sigm(accR[tt][r] + grf[tt][r]);
                    zs[tt][r] = zv;
                    rh[r] = rv * hreg[tt][r];
                }
                unsigned pa = pkbf(rh[0], rh[1]);
                unsigned pb = pkbf(rh[2], rh[3]);
                const int col = w * 32 + tt * 16 + n;
                rh_lds[quad * 4 + 0][col] = (unsigned short)pa;
                rh_lds[quad * 4 + 1][col] = (unsigned short)(pa >> 16);
                rh_lds[quad * 4 + 2][col] = (unsigned short)pb;
                rh_lds[quad * 4 + 3][col] = (unsigned short)(pb >> 16);
            }
        }
        lds_barrier();   // r*h published; h_lds reads complete

        // candidate MFMA (Wc fully register-resident)
        f32x4 accC[2];
#pragma unroll
        for (int tt = 0; tt < 2; ++tt) accC[tt] = z4;
#pragma unroll
        for (int kt = 0; kt < 8; ++kt) {
            s16x8 a = *(const s16x8*)(&rh_lds[rowA][kt * 32 + quad * 8]);
#pragma unroll
            for (int tt = 0; tt < 2; ++tt)
                accC[tt] = __builtin_amdgcn_mfma_f32_16x16x32_bf16(a, Wcr[tt][kt], accC[tt], 0, 0, 0);
        }

        // epilogue 2: extract c Gx, reload ga[4..5] for t+1, candidate, h update, stores
        {
            float gcf[2][4];
#pragma unroll
            for (int tt = 0; tt < 2; ++tt) {
                uint2 gc = ga[4 + tt];
                gcf[tt][0] = bf2f((unsigned short)(gc.x & 0xffffu));
                gcf[tt][1] = bf2f((unsigned short)(gc.x >> 16));
                gcf[tt][2] = bf2f((unsigned short)(gc.y & 0xffffu));
                gcf[tt][3] = bf2f((unsigned short)(gc.y >> 16));
            }
#pragma unroll
            for (int i = 4; i < 6; ++i)
                ga[i] = *(const uint2*)(gbn + 4096 + (i & 1) * 512);
            float* op = outp + (size_t)t * 65536;
#pragma unroll
            for (int tt = 0; tt < 2; ++tt) {
                float hn4[4];
#pragma unroll
                for (int r = 0; r < 4; ++r) {
                    float cv = tanh_(accC[tt][r] + gcf[tt][r]);
                    float h  = hreg[tt][r];
                    float hn = fmaf(zs[tt][r], cv - h, h);
                    hreg[tt][r] = hn;
                    hn4[r] = hn;
                    op[r * 256 + tt * 16] = hn;
                }
                unsigned pa = pkbf(hn4[0], hn4[1]);
                unsigned pb = pkbf(hn4[2], hn4[3]);
                const int col = w * 32 + tt * 16 + n;
                h_lds[quad * 4 + 0][col] = (unsigned short)pa;
                h_lds[quad * 4 + 1][col] = (unsigned short)(pa >> 16);
                h_lds[quad * 4 + 2][col] = (unsigned short)pb;
                h_lds[quad * 4 + 3][col] = (unsigned short)(pb >> 16);
            }
        }
        lds_barrier();   // h published for next step
    }
}

// ---------------------------------------------------------------------------
// Fallback (only if ws too small): naive fp32, correct but slow.
// ---------------------------------------------------------------------------
__global__ __launch_bounds__(1024, 1) void gru_fallback(
    const float* __restrict__ X,
    const float* __restrict__ Wz, const float* __restrict__ bz,
    const float* __restrict__ Wr, const float* __restrict__ br,
    const float* __restrict__ Wc, const float* __restrict__ bc,
    float* __restrict__ out)
{
    __shared__ float h_s[16][257];
    __shared__ float rh_s[16][257];
    __shared__ float x_s[16][128];
    const int tid = threadIdx.x;
    const int wg = blockIdx.x, b0 = wg * 16;
    const int m = tid >> 6, jq = tid & 63;
    for (int i = tid; i < 16 * 257; i += 1024) (&h_s[0][0])[i] = 0.0f;
    __syncthreads();
    for (int t = 0; t < SEQ; ++t) {
        for (int i = tid; i < 2048; i += 1024) {
            int row = i >> 7, k = i & 127;
            x_s[row][k] = X[(size_t)((b0 + row) * SEQ + t) * NI + k];
        }
        __syncthreads();
        float zv[4];
        for (int jj = 0; jj < 4; ++jj) {
            int j = jj * 64 + jq;
            float az = bz[j], ar = br[j];
            for (int k = 0; k < 256; ++k) { float h = h_s[m][k]; az += h * Wz[j * WROW + k]; ar += h * Wr[j * WROW + k]; }
            for (int k = 0; k < 128; ++k) { float x = x_s[m][k]; az += x * Wz[j * WROW + 256 + k]; ar += x * Wr[j * WROW + 256 + k]; }
            float z = sigm(az), r = sigm(ar);
            zv[jj] = z;
            rh_s[m][j] = r * h_s[m][j];
        }
        __syncthreads();
        float hn[4];
        for (int jj = 0; jj < 4; ++jj) {
            int j = jj * 64 + jq;
            float ac = bc[j];
            for (int k = 0; k < 256; ++k) ac += rh_s[m][k] * Wc[j * WROW + k];
            for (int k = 0; k < 128; ++k) ac += x_s[m][k] * Wc[j * WROW + 256 + k];
            float c = tanh_(ac);
            float h = h_s[m][j];
            hn[jj] = fmaf(zv[jj], c - h, h);
        }
        __syncthreads();
        for (int jj = 0; jj < 4; ++jj) {
            int j = jj * 64 + jq;
            h_s[m][j] = hn[jj];
            out[(size_t)(t * 256 + b0 + m) * 256 + j] = hn[jj];
        }
        __syncthreads();
    }
}

extern "C" void kernel_launch(void* const* d_in, const int* in_sizes, int n_in,
                              void* d_out, int out_size, void* d_ws, size_t ws_size,
                              hipStream_t stream) {
    const float* X  = (const float*)d_in[0];
    const float* Wz = (const float*)d_in[1];
    const float* bz = (const float*)d_in[2];
    const float* Wr = (const float*)d_in[3];
    const float* br = (const float*)d_in[4];
    const float* Wc = (const float*)d_in[5];
    const float* bc = (const float*)d_in[6];
    float* out = (float*)d_out;

    if (ws_size >= GX_BYTES + WTAB_BYTES) {
        unsigned short* Gx   = (unsigned short*)d_ws;
        unsigned short* wtab = (unsigned short*)((char*)d_ws + GX_BYTES);
        gru_wprep<<<48, 256, 0, stream>>>(Wz, Wr, Wc, wtab);
        gru_xpre<<<2048, 256, 0, stream>>>(X, bz, br, bc, wtab, Gx);
        gru_seq<<<16, 512, 0, stream>>>(Wz, Wr, Wc, Gx, out);
    } else if (ws_size >= GX_BYTES) {
        unsigned short* Gx = (unsigned short*)d_ws;
        gru_xpre_gather<<<512, 256, 0, stream>>>(X, Wz, bz, Wr, br, Wc, bc, Gx);
        gru_seq<<<16, 512, 0, stream>>>(Wz, Wr, Wc, Gx, out);
    } else {
        gru_fallback<<<16, 1024, 0, stream>>>(X, Wz, bz, Wr, br, Wc, bc, out);
    }
}

// Round 6
// 1154.946 us; speedup vs baseline: 1.2173x; 1.2173x over previous
//
#include <hip/hip_runtime.h>
#include <hip/hip_bf16.h>

// GRU: BATCH=256, SEQ=512, INPUT=128, HIDDEN=256, fp32 in/out.
// Phase 0 (gru_wprep): one-shot gather of X-part weight frags into a 192 KB table.
// Phase 1 (gru_xpre): Gx = X @ W_g[:,256:384].T + b_g (bf16, swizzled chunks).
//   4 WGs per timestep, gate-looped, occupancy 2.
// Phase 2 (gru_seq): persistent batch-split recurrence, 16 WGs x 512 thr.
//   Wz/Wr frags in VGPRs (128), Wc kt0..3 in regs (32), Wc kt4..7 in LDS (64 KB)
//   -- total ~235 regs/wave, fits the 256 unified VGPR+AGPR cap at 2 waves/SIMD
//   (round-5 all-register Wc = ~270 regs -> scratch spills, -246 us).
//   h/rh row pitch HPAD=260 shorts (130 dw == 2 mod 32): A-frag ds_read_b128
//   banks 2n+16kt+4q+e balance over all 32 banks -> SQ_LDS_BANK_CONFLICT
//   4.19M -> 0 (verified round 5). Gx loads pipelined one full step ahead;
//   lgkm-only barriers keep Gx loads / out stores in flight across them.
// Fallback (gru_fallback): naive fp32, used only if ws too small.

typedef float f32x4 __attribute__((ext_vector_type(4)));
typedef short s16x8 __attribute__((ext_vector_type(8)));

#define SEQ 512
#define NB  256
#define NI  128
#define NH  256
#define WROW 384               // W leading dim (H+I)
#define HPAD 260               // h/rh row pitch in shorts (130 dw == 2 mod 32)
#define GX_BYTES ((size_t)201326592)   // 512 t * 768 chunks * 512 B
#define WTAB_BYTES ((size_t)196608)    // 192 frags * 64 lanes * 16 B

static __device__ inline float bf2f(unsigned short s) {
    unsigned u = ((unsigned)s) << 16;
    return __builtin_bit_cast(float, u);
}
// packed f32x2 -> bf16x2 (RTNE) via v_cvt_pk_bf16_f32
static __device__ inline unsigned pkbf(float a, float b) {
    __hip_bfloat162 h = __float22bfloat162_rn(make_float2(a, b));
    unsigned r;
    __builtin_memcpy(&r, &h, 4);
    return r;
}
static __device__ inline s16x8 pk8(f32x4 f0, f32x4 f1) {
    uint4 u;
    u.x = pkbf(f0[0], f0[1]);
    u.y = pkbf(f0[2], f0[3]);
    u.z = pkbf(f1[0], f1[1]);
    u.w = pkbf(f1[2], f1[3]);
    return __builtin_bit_cast(s16x8, u);
}
static __device__ inline float fexp2(float x) {
#if __has_builtin(__builtin_amdgcn_exp2f)
    return __builtin_amdgcn_exp2f(x);
#else
    return exp2f(x);
#endif
}
static __device__ inline float frcp(float x) {
#if __has_builtin(__builtin_amdgcn_rcpf)
    return __builtin_amdgcn_rcpf(x);
#else
    return 1.0f / x;
#endif
}
static __device__ inline float sigm(float x)  { return frcp(1.0f + fexp2(-1.44269504f * x)); }
static __device__ inline float tanh_(float x) { return 1.0f - 2.0f * frcp(1.0f + fexp2(2.88539008f * x)); }

// lgkm-only barrier: LDS visibility without draining vmem (loads/stores stay in flight)
static __device__ inline void lds_barrier() {
    asm volatile("s_waitcnt lgkmcnt(0)\n\ts_barrier" ::: "memory");
}

// ---------------------------------------------------------------------------
// Phase 0: one-shot W-frag table build. 48 WGs x 256 thr -> 12288 tasks.
// ---------------------------------------------------------------------------
__global__ __launch_bounds__(256, 1) void gru_wprep(
    const float* __restrict__ Wz, const float* __restrict__ Wr, const float* __restrict__ Wc,
    unsigned short* __restrict__ wtab)
{
    int task = blockIdx.x * 256 + threadIdx.x;
    int l  = task & 63;
    int fr = task >> 6;            // 0..191
    int v  = fr / 48;
    int f  = fr - v * 48;          // g*16 + tt*4 + kt
    int g  = f >> 4, tt = (f >> 2) & 3, kt = f & 3;
    const float* Wp = (g == 0) ? Wz : (g == 1) ? Wr : Wc;
    int j = v * 64 + tt * 16 + (l & 15);
    const float* src = Wp + (size_t)j * WROW + 256 + kt * 32 + (l >> 4) * 8;
    f32x4 f0 = *(const f32x4*)src;
    f32x4 f1 = *(const f32x4*)(src + 4);
    *(s16x8*)(wtab + (size_t)task * 8) = pk8(f0, f1);
}

// ---------------------------------------------------------------------------
// Phase 1: input projections. 4 WGs per timestep t (mq = batch quarter).
// ---------------------------------------------------------------------------
__global__ __launch_bounds__(256, 2) void gru_xpre(
    const float* __restrict__ X,
    const float* __restrict__ bz, const float* __restrict__ br, const float* __restrict__ bc,
    const unsigned short* __restrict__ wtab,
    unsigned short* __restrict__ Gx)
{
    __shared__ __align__(16) unsigned short x_lds[8192];   // 64 rows x 128 bf16, swizzled
    const int tid  = threadIdx.x;
    const int t    = blockIdx.x >> 2;
    const int mq   = blockIdx.x & 3;
    const int l    = tid & 63;
    const int v    = tid >> 6;
    const int quad = l >> 4;
    const int n    = l & 15;

    for (int i = tid; i < 1024; i += 256) {
        int lr = i >> 4, c = i & 15;
        const float* src = X + (size_t)((mq * 64 + lr) * SEQ + t) * NI + c * 8;
        f32x4 f0 = *(const f32x4*)(src);
        f32x4 f1 = *(const f32x4*)(src + 4);
        *(s16x8*)(&x_lds[lr * 128 + ((c ^ (lr & 15)) << 3)]) = pk8(f0, f1);
    }
    __syncthreads();

    const float* bp[3] = {bz, br, bc};
    const int rowA = n;
#pragma unroll 1
    for (int g = 0; g < 3; ++g) {
        s16x8 Bf[4][4];
        float bias[4];
#pragma unroll
        for (int tt = 0; tt < 4; ++tt) {
            bias[tt] = bp[g][v * 64 + tt * 16 + n];
#pragma unroll
            for (int kt = 0; kt < 4; ++kt)
                Bf[tt][kt] = *(const s16x8*)(wtab
                    + ((size_t)(v * 48 + g * 16 + tt * 4 + kt) * 64 + l) * 8);
        }

#pragma unroll 1
        for (int mtl = 0; mtl < 4; ++mtl) {
            const int mt = mq * 4 + mtl;
            f32x4 acc[4];
            const f32x4 z4 = {0.f, 0.f, 0.f, 0.f};
#pragma unroll
            for (int tt = 0; tt < 4; ++tt) acc[tt] = z4;

#pragma unroll
            for (int kt = 0; kt < 4; ++kt) {
                s16x8 a = *(const s16x8*)(&x_lds[(mtl * 16 + rowA) * 128
                                                 + (((kt * 4 + quad) ^ rowA) << 3)]);
#pragma unroll
                for (int tt = 0; tt < 4; ++tt)
                    acc[tt] = __builtin_amdgcn_mfma_f32_16x16x32_bf16(a, Bf[tt][kt], acc[tt], 0, 0, 0);
            }

#pragma unroll
            for (int tt = 0; tt < 4; ++tt) {
                float b = bias[tt];
                uint2 d;
                d.x = pkbf(acc[tt][0] + b, acc[tt][1] + b);
                d.y = pkbf(acc[tt][2] + b, acc[tt][3] + b);
                int chunk = (((t * 16 + mt) * 4 + v) * 3 + g) * 4 + tt;
                *(uint2*)((char*)Gx + (size_t)chunk * 512 + l * 8) = d;
            }
        }
    }
}

// ---------------------------------------------------------------------------
// Phase 1 (legacy gather variant, used when ws has room for Gx but not wtab)
// ---------------------------------------------------------------------------
__global__ __launch_bounds__(256, 1) void gru_xpre_gather(
    const float* __restrict__ X,
    const float* __restrict__ Wz, const float* __restrict__ bz,
    const float* __restrict__ Wr, const float* __restrict__ br,
    const float* __restrict__ Wc, const float* __restrict__ bc,
    unsigned short* __restrict__ Gx)
{
    __shared__ __align__(16) unsigned short x_lds[32768];
    const int tid  = threadIdx.x;
    const int t    = blockIdx.x;
    const int l    = tid & 63;
    const int v    = tid >> 6;
    const int quad = l >> 4;
    const int n    = l & 15;

    for (int i = tid; i < 4096; i += 256) {
        int row = i >> 4, c = i & 15;
        const float* src = X + (size_t)(row * SEQ + t) * NI + c * 8;
        f32x4 f0 = *(const f32x4*)(src);
        f32x4 f1 = *(const f32x4*)(src + 4);
        *(s16x8*)(&x_lds[row * 128 + ((c ^ (row & 15)) << 3)]) = pk8(f0, f1);
    }

    const float* Wp[3] = {Wz, Wr, Wc};
    const float* bp[3] = {bz, br, bc};
    s16x8 Bf[3][4][4];
    float bias[3][4];
#pragma unroll
    for (int g = 0; g < 3; ++g) {
#pragma unroll
        for (int tt = 0; tt < 4; ++tt) {
            int j = v * 64 + tt * 16 + n;
            bias[g][tt] = bp[g][j];
#pragma unroll
            for (int kt = 0; kt < 4; ++kt) {
                const float* src = Wp[g] + j * WROW + 256 + kt * 32 + quad * 8;
                f32x4 f0 = *(const f32x4*)(src);
                f32x4 f1 = *(const f32x4*)(src + 4);
                Bf[g][tt][kt] = pk8(f0, f1);
            }
        }
    }
    __syncthreads();

    const int rowA = l & 15;
#pragma unroll 1
    for (int mt = 0; mt < 16; ++mt) {
        f32x4 acc[3][4];
        f32x4 z4 = {0.f, 0.f, 0.f, 0.f};
#pragma unroll
        for (int g = 0; g < 3; ++g)
#pragma unroll
            for (int tt = 0; tt < 4; ++tt) acc[g][tt] = z4;

#pragma unroll
        for (int kt = 0; kt < 4; ++kt) {
            int row = mt * 16 + rowA;
            s16x8 a = *(const s16x8*)(&x_lds[row * 128 + (((kt * 4 + quad) ^ rowA) << 3)]);
#pragma unroll
            for (int g = 0; g < 3; ++g)
#pragma unroll
                for (int tt = 0; tt < 4; ++tt)
                    acc[g][tt] = __builtin_amdgcn_mfma_f32_16x16x32_bf16(a, Bf[g][tt][kt], acc[g][tt], 0, 0, 0);
        }

#pragma unroll
        for (int g = 0; g < 3; ++g)
#pragma unroll
            for (int tt = 0; tt < 4; ++tt) {
                float b = bias[g][tt];
                uint2 d;
                d.x = pkbf(acc[g][tt][0] + b, acc[g][tt][1] + b);
                d.y = pkbf(acc[g][tt][2] + b, acc[g][tt][3] + b);
                int chunk = (((t * 16 + mt) * 4 + v) * 3 + g) * 4 + tt;
                *(uint2*)((char*)Gx + (size_t)chunk * 512 + l * 8) = d;
            }
    }
}

// ---------------------------------------------------------------------------
// Phase 2: persistent recurrence. 16 WGs x 512 thr (8 waves, 2 waves/SIMD).
// Each wave handles j = w*32 .. w*32+31 (tt in [0,2)).
// Wz/Wr frags resident in 128 VGPRs; Wc kt0..3 in 32 regs; Wc kt4..7 in LDS (64 KB).
// LDS total: 65536 + 2*16*HPAD*2 = 82176 B. Gx loads pipelined one step ahead.
// ---------------------------------------------------------------------------
__global__ __launch_bounds__(512, 2) void gru_seq(
    const float* __restrict__ Wz, const float* __restrict__ Wr, const float* __restrict__ Wc,
    const unsigned short* __restrict__ Gx,
    float* __restrict__ out)
{
    __shared__ __align__(16) unsigned short wc_lds[32768];  // 64 frags x 64 lanes x 16 B
    __shared__ __align__(16) unsigned short h_lds[16][HPAD];
    __shared__ __align__(16) unsigned short rh_lds[16][HPAD];

    const int tid  = threadIdx.x;
    const int wg   = blockIdx.x;
    const int l    = tid & 63;
    const int w    = tid >> 6;       // wave 0..7
    const int quad = l >> 4;
    const int n    = l & 15;
    const int rowA = n;

    // resident Wz/Wr frags: Wf[g][tt][kt], j = w*32 + tt*16 + n, k = kt*32 + quad*8
    const float* Wp2[2] = {Wz, Wr};
    s16x8 Wf[2][2][8];
#pragma unroll
    for (int g = 0; g < 2; ++g)
#pragma unroll
        for (int tt = 0; tt < 2; ++tt)
#pragma unroll
            for (int kt = 0; kt < 8; ++kt) {
                int j = w * 32 + tt * 16 + n;
                const float* src = Wp2[g] + j * WROW + kt * 32 + quad * 8;
                f32x4 f0 = *(const f32x4*)(src);
                f32x4 f1 = *(const f32x4*)(src + 4);
                Wf[g][tt][kt] = pk8(f0, f1);
            }

    // resident Wc frags for kt 0..3 (same j/k mapping as Wf)
    s16x8 Wcr[2][4];
#pragma unroll
    for (int tt = 0; tt < 2; ++tt)
#pragma unroll
        for (int kt = 0; kt < 4; ++kt) {
            int j = w * 32 + tt * 16 + n;
            const float* src = Wc + j * WROW + kt * 32 + quad * 8;
            f32x4 f0 = *(const f32x4*)(src);
            f32x4 f1 = *(const f32x4*)(src + 4);
            Wcr[tt][kt] = pk8(f0, f1);
        }

    // build Wc frag table in LDS for kt 4..7: frag = jb*4 + (kt-4) (jb in [0,16)),
    // 1 KB each, lane ln holds B[k = kt*32 + (ln>>4)*8 .. +7][j = jb*16 + (ln&15)]
    for (int idx = tid; idx < 4096; idx += 512) {
        int fr = idx >> 6, ln = idx & 63;
        int jb = fr >> 2, ktm = fr & 3;
        int j = jb * 16 + (ln & 15);
        int k = (ktm + 4) * 32 + (ln >> 4) * 8;
        const float* src = Wc + j * WROW + k;
        f32x4 f0 = *(const f32x4*)(src);
        f32x4 f1 = *(const f32x4*)(src + 4);
        *(s16x8*)(&wc_lds[idx * 8]) = pk8(f0, f1);
    }

    // zero h state
    {
        unsigned short* hz = &h_lds[0][0];
        for (int i = tid; i < 16 * HPAD; i += 512) hz[i] = 0;
    }
    float hreg[2][4];
#pragma unroll
    for (int tt = 0; tt < 2; ++tt)
#pragma unroll
        for (int r = 0; r < 4; ++r) hreg[tt][r] = 0.0f;
    __syncthreads();

    // Gx addressing: chunk = ((t*16+wg)*4 + (w>>1))*12 + g*4 + (w&1)*2 + tt
    const char* gxbase = (const char*)Gx
        + (size_t)(((wg * 4 + (w >> 1)) * 12 + (w & 1) * 2) * 512) + l * 8;
    float* outp = out + (size_t)(wg * 16 + quad * 4) * 256 + w * 32 + n;
    const f32x4 z4 = {0.f, 0.f, 0.f, 0.f};

    // preload Gx for t=0
    uint2 ga[6];
#pragma unroll
    for (int i = 0; i < 6; ++i)
        ga[i] = *(const uint2*)(gxbase + (i >> 1) * 2048 + (i & 1) * 512);

#pragma unroll 1
    for (int t = 0; t < SEQ; ++t) {
        const char* gbn = gxbase + (size_t)(t + 1 < SEQ ? t + 1 : t) * 393216;

        // z/r MFMA
        f32x4 accZ[2], accR[2];
#pragma unroll
        for (int tt = 0; tt < 2; ++tt) { accZ[tt] = z4; accR[tt] = z4; }
#pragma unroll
        for (int kt = 0; kt < 8; ++kt) {
            s16x8 a = *(const s16x8*)(&h_lds[rowA][kt * 32 + quad * 8]);
#pragma unroll
            for (int tt = 0; tt < 2; ++tt) {
                accZ[tt] = __builtin_amdgcn_mfma_f32_16x16x32_bf16(a, Wf[0][tt][kt], accZ[tt], 0, 0, 0);
                accR[tt] = __builtin_amdgcn_mfma_f32_16x16x32_bf16(a, Wf[1][tt][kt], accR[tt], 0, 0, 0);
            }
        }

        // epilogue 1: extract z/r Gx, reload ga[0..3] for t+1, compute z, r, write r*h
        float zs[2][4];
        {
            float gzf[2][4], grf[2][4];
#pragma unroll
            for (int tt = 0; tt < 2; ++tt) {
                uint2 gz = ga[tt], gr = ga[2 + tt];
                gzf[tt][0] = bf2f((unsigned short)(gz.x & 0xffffu));
                gzf[tt][1] = bf2f((unsigned short)(gz.x >> 16));
                gzf[tt][2] = bf2f((unsigned short)(gz.y & 0xffffu));
                gzf[tt][3] = bf2f((unsigned short)(gz.y >> 16));
                grf[tt][0] = bf2f((unsigned short)(gr.x & 0xffffu));
                grf[tt][1] = bf2f((unsigned short)(gr.x >> 16));
                grf[tt][2] = bf2f((unsigned short)(gr.y & 0xffffu));
                grf[tt][3] = bf2f((unsigned short)(gr.y >> 16));
            }
#pragma unroll
            for (int i = 0; i < 4; ++i)
                ga[i] = *(const uint2*)(gbn + (i >> 1) * 2048 + (i & 1) * 512);
#pragma unroll
            for (int tt = 0; tt < 2; ++tt) {
                float rh[4];
#pragma unroll
                for (int r = 0; r < 4; ++r) {
                    float zv = sigm(accZ[tt][r] + gzf[tt][r]);
                    float rv = sigm(accR[tt][r] + grf[tt][r]);
                    zs[tt][r] = zv;
                    rh[r] = rv * hreg[tt][r];
                }
                unsigned pa = pkbf(rh[0], rh[1]);
                unsigned pb = pkbf(rh[2], rh[3]);
                const int col = w * 32 + tt * 16 + n;
                rh_lds[quad * 4 + 0][col] = (unsigned short)pa;
                rh_lds[quad * 4 + 1][col] = (unsigned short)(pa >> 16);
                rh_lds[quad * 4 + 2][col] = (unsigned short)pb;
                rh_lds[quad * 4 + 3][col] = (unsigned short)(pb >> 16);
            }
        }
        lds_barrier();   // r*h published; h_lds reads complete

        // candidate MFMA (Wc kt0..3 from regs, kt4..7 from LDS)
        f32x4 accC[2];
#pragma unroll
        for (int tt = 0; tt < 2; ++tt) accC[tt] = z4;
#pragma unroll
        for (int kt = 0; kt < 8; ++kt) {
            s16x8 a = *(const s16x8*)(&rh_lds[rowA][kt * 32 + quad * 8]);
#pragma unroll
            for (int tt = 0; tt < 2; ++tt) {
                s16x8 b = (kt < 4)
                    ? Wcr[tt][kt]
                    : *(const s16x8*)(&wc_lds[(((w * 2 + tt) * 4 + (kt - 4)) * 64 + l) * 8]);
                accC[tt] = __builtin_amdgcn_mfma_f32_16x16x32_bf16(a, b, accC[tt], 0, 0, 0);
            }
        }

        // epilogue 2: extract c Gx, reload ga[4..5] for t+1, candidate, h update, stores
        {
            float gcf[2][4];
#pragma unroll
            for (int tt = 0; tt < 2; ++tt) {
                uint2 gc = ga[4 + tt];
                gcf[tt][0] = bf2f((unsigned short)(gc.x & 0xffffu));
                gcf[tt][1] = bf2f((unsigned short)(gc.x >> 16));
                gcf[tt][2] = bf2f((unsigned short)(gc.y & 0xffffu));
                gcf[tt][3] = bf2f((unsigned short)(gc.y >> 16));
            }
#pragma unroll
            for (int i = 4; i < 6; ++i)
                ga[i] = *(const uint2*)(gbn + 4096 + (i & 1) * 512);
            float* op = outp + (size_t)t * 65536;
#pragma unroll
            for (int tt = 0; tt < 2; ++tt) {
                float hn4[4];
#pragma unroll
                for (int r = 0; r < 4; ++r) {
                    float cv = tanh_(accC[tt][r] + gcf[tt][r]);
                    float h  = hreg[tt][r];
                    float hn = fmaf(zs[tt][r], cv - h, h);
                    hreg[tt][r] = hn;
                    hn4[r] = hn;
                    op[r * 256 + tt * 16] = hn;
                }
                unsigned pa = pkbf(hn4[0], hn4[1]);
                unsigned pb = pkbf(hn4[2], hn4[3]);
                const int col = w * 32 + tt * 16 + n;
                h_lds[quad * 4 + 0][col] = (unsigned short)pa;
                h_lds[quad * 4 + 1][col] = (unsigned short)(pa >> 16);
                h_lds[quad * 4 + 2][col] = (unsigned short)pb;
                h_lds[quad * 4 + 3][col] = (unsigned short)(pb >> 16);
            }
        }
        lds_barrier();   // h published for next step
    }
}

// ---------------------------------------------------------------------------
// Fallback (only if ws too small): naive fp32, correct but slow.
// ---------------------------------------------------------------------------
__global__ __launch_bounds__(1024, 1) void gru_fallback(
    const float* __restrict__ X,
    const float* __restrict__ Wz, const float* __restrict__ bz,
    const float* __restrict__ Wr, const float* __restrict__ br,
    const float* __restrict__ Wc, const float* __restrict__ bc,
    float* __restrict__ out)
{
    __shared__ float h_s[16][257];
    __shared__ float rh_s[16][257];
    __shared__ float x_s[16][128];
    const int tid = threadIdx.x;
    const int wg = blockIdx.x, b0 = wg * 16;
    const int m = tid >> 6, jq = tid & 63;
    for (int i = tid; i < 16 * 257; i += 1024) (&h_s[0][0])[i] = 0.0f;
    __syncthreads();
    for (int t = 0; t < SEQ; ++t) {
        for (int i = tid; i < 2048; i += 1024) {
            int row = i >> 7, k = i & 127;
            x_s[row][k] = X[(size_t)((b0 + row) * SEQ + t) * NI + k];
        }
        __syncthreads();
        float zv[4];
        for (int jj = 0; jj < 4; ++jj) {
            int j = jj * 64 + jq;
            float az = bz[j], ar = br[j];
            for (int k = 0; k < 256; ++k) { float h = h_s[m][k]; az += h * Wz[j * WROW + k]; ar += h * Wr[j * WROW + k]; }
            for (int k = 0; k < 128; ++k) { float x = x_s[m][k]; az += x * Wz[j * WROW + 256 + k]; ar += x * Wr[j * WROW + 256 + k]; }
            float z = sigm(az), r = sigm(ar);
            zv[jj] = z;
            rh_s[m][j] = r * h_s[m][j];
        }
        __syncthreads();
        float hn[4];
        for (int jj = 0; jj < 4; ++jj) {
            int j = jj * 64 + jq;
            float ac = bc[j];
            for (int k = 0; k < 256; ++k) ac += rh_s[m][k] * Wc[j * WROW + k];
            for (int k = 0; k < 128; ++k) ac += x_s[m][k] * Wc[j * WROW + 256 + k];
            float c = tanh_(ac);
            float h = h_s[m][j];
            hn[jj] = fmaf(zv[jj], c - h, h);
        }
        __syncthreads();
        for (int jj = 0; jj < 4; ++jj) {
            int j = jj * 64 + jq;
            h_s[m][j] = hn[jj];
            out[(size_t)(t * 256 + b0 + m) * 256 + j] = hn[jj];
        }
        __syncthreads();
    }
}

extern "C" void kernel_launch(void* const* d_in, const int* in_sizes, int n_in,
                              void* d_out, int out_size, void* d_ws, size_t ws_size,
                              hipStream_t stream) {
    const float* X  = (const float*)d_in[0];
    const float* Wz = (const float*)d_in[1];
    const float* bz = (const float*)d_in[2];
    const float* Wr = (const float*)d_in[3];
    const float* br = (const float*)d_in[4];
    const float* Wc = (const float*)d_in[5];
    const float* bc = (const float*)d_in[6];
    float* out = (float*)d_out;

    if (ws_size >= GX_BYTES + WTAB_BYTES) {
        unsigned short* Gx   = (unsigned short*)d_ws;
        unsigned short* wtab = (unsigned short*)((char*)d_ws + GX_BYTES);
        gru_wprep<<<48, 256, 0, stream>>>(Wz, Wr, Wc, wtab);
        gru_xpre<<<2048, 256, 0, stream>>>(X, bz, br, bc, wtab, Gx);
        gru_seq<<<16, 512, 0, stream>>>(Wz, Wr, Wc, Gx, out);
    } else if (ws_size >= GX_BYTES) {
        unsigned short* Gx = (unsigned short*)d_ws;
        gru_xpre_gather<<<512, 256, 0, stream>>>(X, Wz, bz, Wr, br, Wc, bc, Gx);
        gru_seq<<<16, 512, 0, stream>>>(Wz, Wr, Wc, Gx, out);
    } else {
        gru_fallback<<<16, 1024, 0, stream>>>(X, Wz, bz, Wr, br, Wc, bc, out);
    }
}

// Round 7
// 1121.449 us; speedup vs baseline: 1.2536x; 1.0299x over previous
//
#include <hip/hip_runtime.h>
#include <hip/hip_bf16.h>

// GRU: BATCH=256, SEQ=512, INPUT=128, HIDDEN=256, fp32 in/out.
// Phase 0 (gru_wprep): one-shot gather of X-part weight frags into a 192 KB table.
// Phase 1 (gru_xpre): Gx = X @ W_g[:,256:384].T + b_g (bf16, swizzled chunks).
// Phase 2 (gru_seq): persistent batch-split recurrence, 16 WGs x 512 thr.
//   Wz/Wr frags in VGPRs (128), Wc kt0..3 in regs (32), Wc kt4..7 in LDS (64 KB).
//   h/rh pitch HPAD=260 (conflict-free, verified r5/r6: SQ_LDS_BANK_CONFLICT=0).
//   r7: wc frags kt4..5 prefetched into 16 transient regs during epilogue 1
//   (before bar1) -- shrinks the phase-B LDS read burst 128->96 reads/CU
//   (phase-start read bursts are the measured dominant step cost; r6 showed
//   conflict removal alone = null).
//   Gx loads pipelined one step ahead; lgkm-only barriers keep vmem in flight.
// Fallback (gru_fallback): naive fp32, used only if ws too small.

typedef float f32x4 __attribute__((ext_vector_type(4)));
typedef short s16x8 __attribute__((ext_vector_type(8)));

#define SEQ 512
#define NB  256
#define NI  128
#define NH  256
#define WROW 384               // W leading dim (H+I)
#define HPAD 260               // h/rh row pitch in shorts (130 dw == 2 mod 32)
#define GX_BYTES ((size_t)201326592)   // 512 t * 768 chunks * 512 B
#define WTAB_BYTES ((size_t)196608)    // 192 frags * 64 lanes * 16 B

static __device__ inline float bf2f(unsigned short s) {
    unsigned u = ((unsigned)s) << 16;
    return __builtin_bit_cast(float, u);
}
// packed f32x2 -> bf16x2 (RTNE) via v_cvt_pk_bf16_f32
static __device__ inline unsigned pkbf(float a, float b) {
    __hip_bfloat162 h = __float22bfloat162_rn(make_float2(a, b));
    unsigned r;
    __builtin_memcpy(&r, &h, 4);
    return r;
}
static __device__ inline s16x8 pk8(f32x4 f0, f32x4 f1) {
    uint4 u;
    u.x = pkbf(f0[0], f0[1]);
    u.y = pkbf(f0[2], f0[3]);
    u.z = pkbf(f1[0], f1[1]);
    u.w = pkbf(f1[2], f1[3]);
    return __builtin_bit_cast(s16x8, u);
}
static __device__ inline float fexp2(float x) {
#if __has_builtin(__builtin_amdgcn_exp2f)
    return __builtin_amdgcn_exp2f(x);
#else
    return exp2f(x);
#endif
}
static __device__ inline float frcp(float x) {
#if __has_builtin(__builtin_amdgcn_rcpf)
    return __builtin_amdgcn_rcpf(x);
#else
    return 1.0f / x;
#endif
}
static __device__ inline float sigm(float x)  { return frcp(1.0f + fexp2(-1.44269504f * x)); }
static __device__ inline float tanh_(float x) { return 1.0f - 2.0f * frcp(1.0f + fexp2(2.88539008f * x)); }

// lgkm-only barrier: LDS visibility without draining vmem (loads/stores stay in flight)
static __device__ inline void lds_barrier() {
    asm volatile("s_waitcnt lgkmcnt(0)\n\ts_barrier" ::: "memory");
}

// ---------------------------------------------------------------------------
// Phase 0: one-shot W-frag table build. 48 WGs x 256 thr -> 12288 tasks.
// ---------------------------------------------------------------------------
__global__ __launch_bounds__(256, 1) void gru_wprep(
    const float* __restrict__ Wz, const float* __restrict__ Wr, const float* __restrict__ Wc,
    unsigned short* __restrict__ wtab)
{
    int task = blockIdx.x * 256 + threadIdx.x;
    int l  = task & 63;
    int fr = task >> 6;            // 0..191
    int v  = fr / 48;
    int f  = fr - v * 48;          // g*16 + tt*4 + kt
    int g  = f >> 4, tt = (f >> 2) & 3, kt = f & 3;
    const float* Wp = (g == 0) ? Wz : (g == 1) ? Wr : Wc;
    int j = v * 64 + tt * 16 + (l & 15);
    const float* src = Wp + (size_t)j * WROW + 256 + kt * 32 + (l >> 4) * 8;
    f32x4 f0 = *(const f32x4*)src;
    f32x4 f1 = *(const f32x4*)(src + 4);
    *(s16x8*)(wtab + (size_t)task * 8) = pk8(f0, f1);
}

// ---------------------------------------------------------------------------
// Phase 1: input projections. 4 WGs per timestep t (mq = batch quarter).
// ---------------------------------------------------------------------------
__global__ __launch_bounds__(256, 2) void gru_xpre(
    const float* __restrict__ X,
    const float* __restrict__ bz, const float* __restrict__ br, const float* __restrict__ bc,
    const unsigned short* __restrict__ wtab,
    unsigned short* __restrict__ Gx)
{
    __shared__ __align__(16) unsigned short x_lds[8192];   // 64 rows x 128 bf16, swizzled
    const int tid  = threadIdx.x;
    const int t    = blockIdx.x >> 2;
    const int mq   = blockIdx.x & 3;
    const int l    = tid & 63;
    const int v    = tid >> 6;
    const int quad = l >> 4;
    const int n    = l & 15;

    for (int i = tid; i < 1024; i += 256) {
        int lr = i >> 4, c = i & 15;
        const float* src = X + (size_t)((mq * 64 + lr) * SEQ + t) * NI + c * 8;
        f32x4 f0 = *(const f32x4*)(src);
        f32x4 f1 = *(const f32x4*)(src + 4);
        *(s16x8*)(&x_lds[lr * 128 + ((c ^ (lr & 15)) << 3)]) = pk8(f0, f1);
    }
    __syncthreads();

    const float* bp[3] = {bz, br, bc};
    const int rowA = n;
#pragma unroll 1
    for (int g = 0; g < 3; ++g) {
        s16x8 Bf[4][4];
        float bias[4];
#pragma unroll
        for (int tt = 0; tt < 4; ++tt) {
            bias[tt] = bp[g][v * 64 + tt * 16 + n];
#pragma unroll
            for (int kt = 0; kt < 4; ++kt)
                Bf[tt][kt] = *(const s16x8*)(wtab
                    + ((size_t)(v * 48 + g * 16 + tt * 4 + kt) * 64 + l) * 8);
        }

#pragma unroll 1
        for (int mtl = 0; mtl < 4; ++mtl) {
            const int mt = mq * 4 + mtl;
            f32x4 acc[4];
            const f32x4 z4 = {0.f, 0.f, 0.f, 0.f};
#pragma unroll
            for (int tt = 0; tt < 4; ++tt) acc[tt] = z4;

#pragma unroll
            for (int kt = 0; kt < 4; ++kt) {
                s16x8 a = *(const s16x8*)(&x_lds[(mtl * 16 + rowA) * 128
                                                 + (((kt * 4 + quad) ^ rowA) << 3)]);
#pragma unroll
                for (int tt = 0; tt < 4; ++tt)
                    acc[tt] = __builtin_amdgcn_mfma_f32_16x16x32_bf16(a, Bf[tt][kt], acc[tt], 0, 0, 0);
            }

#pragma unroll
            for (int tt = 0; tt < 4; ++tt) {
                float b = bias[tt];
                uint2 d;
                d.x = pkbf(acc[tt][0] + b, acc[tt][1] + b);
                d.y = pkbf(acc[tt][2] + b, acc[tt][3] + b);
                int chunk = (((t * 16 + mt) * 4 + v) * 3 + g) * 4 + tt;
                *(uint2*)((char*)Gx + (size_t)chunk * 512 + l * 8) = d;
            }
        }
    }
}

// ---------------------------------------------------------------------------
// Phase 1 (legacy gather variant, used when ws has room for Gx but not wtab)
// ---------------------------------------------------------------------------
__global__ __launch_bounds__(256, 1) void gru_xpre_gather(
    const float* __restrict__ X,
    const float* __restrict__ Wz, const float* __restrict__ bz,
    const float* __restrict__ Wr, const float* __restrict__ br,
    const float* __restrict__ Wc, const float* __restrict__ bc,
    unsigned short* __restrict__ Gx)
{
    __shared__ __align__(16) unsigned short x_lds[32768];
    const int tid  = threadIdx.x;
    const int t    = blockIdx.x;
    const int l    = tid & 63;
    const int v    = tid >> 6;
    const int quad = l >> 4;
    const int n    = l & 15;

    for (int i = tid; i < 4096; i += 256) {
        int row = i >> 4, c = i & 15;
        const float* src = X + (size_t)(row * SEQ + t) * NI + c * 8;
        f32x4 f0 = *(const f32x4*)(src);
        f32x4 f1 = *(const f32x4*)(src + 4);
        *(s16x8*)(&x_lds[row * 128 + ((c ^ (row & 15)) << 3)]) = pk8(f0, f1);
    }

    const float* Wp[3] = {Wz, Wr, Wc};
    const float* bp[3] = {bz, br, bc};
    s16x8 Bf[3][4][4];
    float bias[3][4];
#pragma unroll
    for (int g = 0; g < 3; ++g) {
#pragma unroll
        for (int tt = 0; tt < 4; ++tt) {
            int j = v * 64 + tt * 16 + n;
            bias[g][tt] = bp[g][j];
#pragma unroll
            for (int kt = 0; kt < 4; ++kt) {
                const float* src = Wp[g] + j * WROW + 256 + kt * 32 + quad * 8;
                f32x4 f0 = *(const f32x4*)(src);
                f32x4 f1 = *(const f32x4*)(src + 4);
                Bf[g][tt][kt] = pk8(f0, f1);
            }
        }
    }
    __syncthreads();

    const int rowA = l & 15;
#pragma unroll 1
    for (int mt = 0; mt < 16; ++mt) {
        f32x4 acc[3][4];
        f32x4 z4 = {0.f, 0.f, 0.f, 0.f};
#pragma unroll
        for (int g = 0; g < 3; ++g)
#pragma unroll
            for (int tt = 0; tt < 4; ++tt) acc[g][tt] = z4;

#pragma unroll
        for (int kt = 0; kt < 4; ++kt) {
            int row = mt * 16 + rowA;
            s16x8 a = *(const s16x8*)(&x_lds[row * 128 + (((kt * 4 + quad) ^ rowA) << 3)]);
#pragma unroll
            for (int g = 0; g < 3; ++g)
#pragma unroll
                for (int tt = 0; tt < 4; ++tt)
                    acc[g][tt] = __builtin_amdgcn_mfma_f32_16x16x32_bf16(a, Bf[g][tt][kt], acc[g][tt], 0, 0, 0);
        }

#pragma unroll
        for (int g = 0; g < 3; ++g)
#pragma unroll
            for (int tt = 0; tt < 4; ++tt) {
                float b = bias[g][tt];
                uint2 d;
                d.x = pkbf(acc[g][tt][0] + b, acc[g][tt][1] + b);
                d.y = pkbf(acc[g][tt][2] + b, acc[g][tt][3] + b);
                int chunk = (((t * 16 + mt) * 4 + v) * 3 + g) * 4 + tt;
                *(uint2*)((char*)Gx + (size_t)chunk * 512 + l * 8) = d;
            }
    }
}

// ---------------------------------------------------------------------------
// Phase 2: persistent recurrence. 16 WGs x 512 thr (8 waves, 2 waves/SIMD).
// ---------------------------------------------------------------------------
__global__ __launch_bounds__(512, 2) void gru_seq(
    const float* __restrict__ Wz, const float* __restrict__ Wr, const float* __restrict__ Wc,
    const unsigned short* __restrict__ Gx,
    float* __restrict__ out)
{
    __shared__ __align__(16) unsigned short wc_lds[32768];  // 64 frags x 64 lanes x 16 B
    __shared__ __align__(16) unsigned short h_lds[16][HPAD];
    __shared__ __align__(16) unsigned short rh_lds[16][HPAD];

    const int tid  = threadIdx.x;
    const int wg   = blockIdx.x;
    const int l    = tid & 63;
    const int w    = tid >> 6;       // wave 0..7
    const int quad = l >> 4;
    const int n    = l & 15;
    const int rowA = n;

    // resident Wz/Wr frags: Wf[g][tt][kt], j = w*32 + tt*16 + n, k = kt*32 + quad*8
    const float* Wp2[2] = {Wz, Wr};
    s16x8 Wf[2][2][8];
#pragma unroll
    for (int g = 0; g < 2; ++g)
#pragma unroll
        for (int tt = 0; tt < 2; ++tt)
#pragma unroll
            for (int kt = 0; kt < 8; ++kt) {
                int j = w * 32 + tt * 16 + n;
                const float* src = Wp2[g] + j * WROW + kt * 32 + quad * 8;
                f32x4 f0 = *(const f32x4*)(src);
                f32x4 f1 = *(const f32x4*)(src + 4);
                Wf[g][tt][kt] = pk8(f0, f1);
            }

    // resident Wc frags for kt 0..3 (same j/k mapping as Wf)
    s16x8 Wcr[2][4];
#pragma unroll
    for (int tt = 0; tt < 2; ++tt)
#pragma unroll
        for (int kt = 0; kt < 4; ++kt) {
            int j = w * 32 + tt * 16 + n;
            const float* src = Wc + j * WROW + kt * 32 + quad * 8;
            f32x4 f0 = *(const f32x4*)(src);
            f32x4 f1 = *(const f32x4*)(src + 4);
            Wcr[tt][kt] = pk8(f0, f1);
        }

    // build Wc frag table in LDS for kt 4..7: frag = jb*4 + (kt-4) (jb in [0,16)),
    // 1 KB each, lane ln holds B[k = kt*32 + (ln>>4)*8 .. +7][j = jb*16 + (ln&15)]
    for (int idx = tid; idx < 4096; idx += 512) {
        int fr = idx >> 6, ln = idx & 63;
        int jb = fr >> 2, ktm = fr & 3;
        int j = jb * 16 + (ln & 15);
        int k = (ktm + 4) * 32 + (ln >> 4) * 8;
        const float* src = Wc + j * WROW + k;
        f32x4 f0 = *(const f32x4*)(src);
        f32x4 f1 = *(const f32x4*)(src + 4);
        *(s16x8*)(&wc_lds[idx * 8]) = pk8(f0, f1);
    }

    // zero h state
    {
        unsigned short* hz = &h_lds[0][0];
        for (int i = tid; i < 16 * HPAD; i += 512) hz[i] = 0;
    }
    float hreg[2][4];
#pragma unroll
    for (int tt = 0; tt < 2; ++tt)
#pragma unroll
        for (int r = 0; r < 4; ++r) hreg[tt][r] = 0.0f;
    __syncthreads();

    // Gx addressing: chunk = ((t*16+wg)*4 + (w>>1))*12 + g*4 + (w&1)*2 + tt
    const char* gxbase = (const char*)Gx
        + (size_t)(((wg * 4 + (w >> 1)) * 12 + (w & 1) * 2) * 512) + l * 8;
    float* outp = out + (size_t)(wg * 16 + quad * 4) * 256 + w * 32 + n;
    const f32x4 z4 = {0.f, 0.f, 0.f, 0.f};

    // preload Gx for t=0
    uint2 ga[6];
#pragma unroll
    for (int i = 0; i < 6; ++i)
        ga[i] = *(const uint2*)(gxbase + (i >> 1) * 2048 + (i & 1) * 512);

#pragma unroll 1
    for (int t = 0; t < SEQ; ++t) {
        const char* gbn = gxbase + (size_t)(t + 1 < SEQ ? t + 1 : t) * 393216;

        // z/r MFMA
        f32x4 accZ[2], accR[2];
#pragma unroll
        for (int tt = 0; tt < 2; ++tt) { accZ[tt] = z4; accR[tt] = z4; }
#pragma unroll
        for (int kt = 0; kt < 8; ++kt) {
            s16x8 a = *(const s16x8*)(&h_lds[rowA][kt * 32 + quad * 8]);
#pragma unroll
            for (int tt = 0; tt < 2; ++tt) {
                accZ[tt] = __builtin_amdgcn_mfma_f32_16x16x32_bf16(a, Wf[0][tt][kt], accZ[tt], 0, 0, 0);
                accR[tt] = __builtin_amdgcn_mfma_f32_16x16x32_bf16(a, Wf[1][tt][kt], accR[tt], 0, 0, 0);
            }
        }

        // epilogue 1: extract z/r Gx, reload ga[0..3] (t+1), prefetch wc kt4..5
        // into regs (issues on idle ds pipe, completes at bar1's lgkmcnt(0)),
        // compute z, r, write r*h.
        float zs[2][4];
        s16x8 Wcp[2][2];
        {
            float gzf[2][4], grf[2][4];
#pragma unroll
            for (int tt = 0; tt < 2; ++tt) {
                uint2 gz = ga[tt], gr = ga[2 + tt];
                gzf[tt][0] = bf2f((unsigned short)(gz.x & 0xffffu));
                gzf[tt][1] = bf2f((unsigned short)(gz.x >> 16));
                gzf[tt][2] = bf2f((unsigned short)(gz.y & 0xffffu));
                gzf[tt][3] = bf2f((unsigned short)(gz.y >> 16));
                grf[tt][0] = bf2f((unsigned short)(gr.x & 0xffffu));
                grf[tt][1] = bf2f((unsigned short)(gr.x >> 16));
                grf[tt][2] = bf2f((unsigned short)(gr.y & 0xffffu));
                grf[tt][3] = bf2f((unsigned short)(gr.y >> 16));
            }
#pragma unroll
            for (int i = 0; i < 4; ++i)
                ga[i] = *(const uint2*)(gbn + (i >> 1) * 2048 + (i & 1) * 512);
#pragma unroll
            for (int tt = 0; tt < 2; ++tt)
#pragma unroll
                for (int k2 = 0; k2 < 2; ++k2)
                    Wcp[tt][k2] = *(const s16x8*)(&wc_lds[(((w * 2 + tt) * 4 + k2) * 64 + l) * 8]);
#pragma unroll
            for (int tt = 0; tt < 2; ++tt) {
                float rh[4];
#pragma unroll
                for (int r = 0; r < 4; ++r) {
                    float zv = sigm(accZ[tt][r] + gzf[tt][r]);
                    float rv = sigm(accR[tt][r] + grf[tt][r]);
                    zs[tt][r] = zv;
                    rh[r] = rv * hreg[tt][r];
                }
                unsigned pa = pkbf(rh[0], rh[1]);
                unsigned pb = pkbf(rh[2], rh[3]);
                const int col = w * 32 + tt * 16 + n;
                rh_lds[quad * 4 + 0][col] = (unsigned short)pa;
                rh_lds[quad * 4 + 1][col] = (unsigned short)(pa >> 16);
                rh_lds[quad * 4 + 2][col] = (unsigned short)pb;
                rh_lds[quad * 4 + 3][col] = (unsigned short)(pb >> 16);
            }
        }
        lds_barrier();   // r*h published; h_lds reads + Wcp prefetch complete

        // candidate MFMA (Wc kt0..3 regs, kt4..5 prefetched regs, kt6..7 LDS)
        f32x4 accC[2];
#pragma unroll
        for (int tt = 0; tt < 2; ++tt) accC[tt] = z4;
#pragma unroll
        for (int kt = 0; kt < 8; ++kt) {
            s16x8 a = *(const s16x8*)(&rh_lds[rowA][kt * 32 + quad * 8]);
#pragma unroll
            for (int tt = 0; tt < 2; ++tt) {
                s16x8 b = (kt < 4) ? Wcr[tt][kt]
                        : (kt < 6) ? Wcp[tt][kt - 4]
                        : *(const s16x8*)(&wc_lds[(((w * 2 + tt) * 4 + (kt - 4)) * 64 + l) * 8]);
                accC[tt] = __builtin_amdgcn_mfma_f32_16x16x32_bf16(a, b, accC[tt], 0, 0, 0);
            }
        }

        // epilogue 2: extract c Gx, reload ga[4..5] for t+1, candidate, h update, stores
        {
            float gcf[2][4];
#pragma unroll
            for (int tt = 0; tt < 2; ++tt) {
                uint2 gc = ga[4 + tt];
                gcf[tt][0] = bf2f((unsigned short)(gc.x & 0xffffu));
                gcf[tt][1] = bf2f((unsigned short)(gc.x >> 16));
                gcf[tt][2] = bf2f((unsigned short)(gc.y & 0xffffu));
                gcf[tt][3] = bf2f((unsigned short)(gc.y >> 16));
            }
#pragma unroll
            for (int i = 4; i < 6; ++i)
                ga[i] = *(const uint2*)(gbn + 4096 + (i & 1) * 512);
            float* op = outp + (size_t)t * 65536;
#pragma unroll
            for (int tt = 0; tt < 2; ++tt) {
                float hn4[4];
#pragma unroll
                for (int r = 0; r < 4; ++r) {
                    float cv = tanh_(accC[tt][r] + gcf[tt][r]);
                    float h  = hreg[tt][r];
                    float hn = fmaf(zs[tt][r], cv - h, h);
                    hreg[tt][r] = hn;
                    hn4[r] = hn;
                }
                unsigned pa = pkbf(hn4[0], hn4[1]);
                unsigned pb = pkbf(hn4[2], hn4[3]);
                const int col = w * 32 + tt * 16 + n;
                h_lds[quad * 4 + 0][col] = (unsigned short)pa;
                h_lds[quad * 4 + 1][col] = (unsigned short)(pa >> 16);
                h_lds[quad * 4 + 2][col] = (unsigned short)pb;
                h_lds[quad * 4 + 3][col] = (unsigned short)(pb >> 16);
#pragma unroll
                for (int r = 0; r < 4; ++r)
                    op[r * 256 + tt * 16] = hn4[r];
            }
        }
        lds_barrier();   // h published for next step
    }
}

// ---------------------------------------------------------------------------
// Fallback (only if ws too small): naive fp32, correct but slow.
// ---------------------------------------------------------------------------
__global__ __launch_bounds__(1024, 1) void gru_fallback(
    const float* __restrict__ X,
    const float* __restrict__ Wz, const float* __restrict__ bz,
    const float* __restrict__ Wr, const float* __restrict__ br,
    const float* __restrict__ Wc, const float* __restrict__ bc,
    float* __restrict__ out)
{
    __shared__ float h_s[16][257];
    __shared__ float rh_s[16][257];
    __shared__ float x_s[16][128];
    const int tid = threadIdx.x;
    const int wg = blockIdx.x, b0 = wg * 16;
    const int m = tid >> 6, jq = tid & 63;
    for (int i = tid; i < 16 * 257; i += 1024) (&h_s[0][0])[i] = 0.0f;
    __syncthreads();
    for (int t = 0; t < SEQ; ++t) {
        for (int i = tid; i < 2048; i += 1024) {
            int row = i >> 7, k = i & 127;
            x_s[row][k] = X[(size_t)((b0 + row) * SEQ + t) * NI + k];
        }
        __syncthreads();
        float zv[4];
        for (int jj = 0; jj < 4; ++jj) {
            int j = jj * 64 + jq;
            float az = bz[j], ar = br[j];
            for (int k = 0; k < 256; ++k) { float h = h_s[m][k]; az += h * Wz[j * WROW + k]; ar += h * Wr[j * WROW + k]; }
            for (int k = 0; k < 128; ++k) { float x = x_s[m][k]; az += x * Wz[j * WROW + 256 + k]; ar += x * Wr[j * WROW + 256 + k]; }
            float z = sigm(az), r = sigm(ar);
            zv[jj] = z;
            rh_s[m][j] = r * h_s[m][j];
        }
        __syncthreads();
        float hn[4];
        for (int jj = 0; jj < 4; ++jj) {
            int j = jj * 64 + jq;
            float ac = bc[j];
            for (int k = 0; k < 256; ++k) ac += rh_s[m][k] * Wc[j * WROW + k];
            for (int k = 0; k < 128; ++k) ac += x_s[m][k] * Wc[j * WROW + 256 + k];
            float c = tanh_(ac);
            float h = h_s[m][j];
            hn[jj] = fmaf(zv[jj], c - h, h);
        }
        __syncthreads();
        for (int jj = 0; jj < 4; ++jj) {
            int j = jj * 64 + jq;
            h_s[m][j] = hn[jj];
            out[(size_t)(t * 256 + b0 + m) * 256 + j] = hn[jj];
        }
        __syncthreads();
    }
}

extern "C" void kernel_launch(void* const* d_in, const int* in_sizes, int n_in,
                              void* d_out, int out_size, void* d_ws, size_t ws_size,
                              hipStream_t stream) {
    const float* X  = (const float*)d_in[0];
    const float* Wz = (const float*)d_in[1];
    const float* bz = (const float*)d_in[2];
    const float* Wr = (const float*)d_in[3];
    const float* br = (const float*)d_in[4];
    const float* Wc = (const float*)d_in[5];
    const float* bc = (const float*)d_in[6];
    float* out = (float*)d_out;

    if (ws_size >= GX_BYTES + WTAB_BYTES) {
        unsigned short* Gx   = (unsigned short*)d_ws;
        unsigned short* wtab = (unsigned short*)((char*)d_ws + GX_BYTES);
        gru_wprep<<<48, 256, 0, stream>>>(Wz, Wr, Wc, wtab);
        gru_xpre<<<2048, 256, 0, stream>>>(X, bz, br, bc, wtab, Gx);
        gru_seq<<<16, 512, 0, stream>>>(Wz, Wr, Wc, Gx, out);
    } else if (ws_size >= GX_BYTES) {
        unsigned short* Gx = (unsigned short*)d_ws;
        gru_xpre_gather<<<512, 256, 0, stream>>>(X, Wz, bz, Wr, br, Wc, bc, Gx);
        gru_seq<<<16, 512, 0, stream>>>(Wz, Wr, Wc, Gx, out);
    } else {
        gru_fallback<<<16, 1024, 0, stream>>>(X, Wz, bz, Wr, br, Wc, bc, out);
    }
}

// Round 8
// 1119.891 us; speedup vs baseline: 1.2554x; 1.0014x over previous
//
#include <hip/hip_runtime.h>
#include <hip/hip_bf16.h>

// GRU: BATCH=256, SEQ=512, INPUT=128, HIDDEN=256, fp32 in/out.
// Phase 0 (gru_wprep): one-shot gather of X-part weight frags into a 192 KB table.
// Phase 1 (gru_xpre): Gx = X @ W_g[:,256:384].T + b_g (bf16, swizzled chunks).
// Phase 2 (gru_seq): persistent batch-split recurrence, 16 WGs x 512 thr.
//   Wz/Wr frags in VGPRs (128), Wc kt0..3 in regs (32), Wc kt4..7 staged in LDS
//   but prefetched into 32 transient regs during epilogue 1 (r7: kt4..5 = -23us,
//   r8 extends to kt6..7) -- phase-B LDS burst is now rh A-frags only (64 reads).
//   h/rh pitch HPAD=260 (conflict-free, r5/r6: SQ_LDS_BANK_CONFLICT=0).
//   Gx loads pipelined one step ahead; lgkm-only barriers keep vmem in flight.
// Fallback (gru_fallback): naive fp32, used only if ws too small.

typedef float f32x4 __attribute__((ext_vector_type(4)));
typedef short s16x8 __attribute__((ext_vector_type(8)));

#define SEQ 512
#define NB  256
#define NI  128
#define NH  256
#define WROW 384               // W leading dim (H+I)
#define HPAD 260               // h/rh row pitch in shorts (130 dw == 2 mod 32)
#define GX_BYTES ((size_t)201326592)   // 512 t * 768 chunks * 512 B
#define WTAB_BYTES ((size_t)196608)    // 192 frags * 64 lanes * 16 B

static __device__ inline float bf2f(unsigned short s) {
    unsigned u = ((unsigned)s) << 16;
    return __builtin_bit_cast(float, u);
}
// packed f32x2 -> bf16x2 (RTNE) via v_cvt_pk_bf16_f32
static __device__ inline unsigned pkbf(float a, float b) {
    __hip_bfloat162 h = __float22bfloat162_rn(make_float2(a, b));
    unsigned r;
    __builtin_memcpy(&r, &h, 4);
    return r;
}
static __device__ inline s16x8 pk8(f32x4 f0, f32x4 f1) {
    uint4 u;
    u.x = pkbf(f0[0], f0[1]);
    u.y = pkbf(f0[2], f0[3]);
    u.z = pkbf(f1[0], f1[1]);
    u.w = pkbf(f1[2], f1[3]);
    return __builtin_bit_cast(s16x8, u);
}
static __device__ inline float fexp2(float x) {
#if __has_builtin(__builtin_amdgcn_exp2f)
    return __builtin_amdgcn_exp2f(x);
#else
    return exp2f(x);
#endif
}
static __device__ inline float frcp(float x) {
#if __has_builtin(__builtin_amdgcn_rcpf)
    return __builtin_amdgcn_rcpf(x);
#else
    return 1.0f / x;
#endif
}
static __device__ inline float sigm(float x)  { return frcp(1.0f + fexp2(-1.44269504f * x)); }
static __device__ inline float tanh_(float x) { return 1.0f - 2.0f * frcp(1.0f + fexp2(2.88539008f * x)); }

// lgkm-only barrier: LDS visibility without draining vmem (loads/stores stay in flight)
static __device__ inline void lds_barrier() {
    asm volatile("s_waitcnt lgkmcnt(0)\n\ts_barrier" ::: "memory");
}

// ---------------------------------------------------------------------------
// Phase 0: one-shot W-frag table build. 48 WGs x 256 thr -> 12288 tasks.
// ---------------------------------------------------------------------------
__global__ __launch_bounds__(256, 1) void gru_wprep(
    const float* __restrict__ Wz, const float* __restrict__ Wr, const float* __restrict__ Wc,
    unsigned short* __restrict__ wtab)
{
    int task = blockIdx.x * 256 + threadIdx.x;
    int l  = task & 63;
    int fr = task >> 6;            // 0..191
    int v  = fr / 48;
    int f  = fr - v * 48;          // g*16 + tt*4 + kt
    int g  = f >> 4, tt = (f >> 2) & 3, kt = f & 3;
    const float* Wp = (g == 0) ? Wz : (g == 1) ? Wr : Wc;
    int j = v * 64 + tt * 16 + (l & 15);
    const float* src = Wp + (size_t)j * WROW + 256 + kt * 32 + (l >> 4) * 8;
    f32x4 f0 = *(const f32x4*)src;
    f32x4 f1 = *(const f32x4*)(src + 4);
    *(s16x8*)(wtab + (size_t)task * 8) = pk8(f0, f1);
}

// ---------------------------------------------------------------------------
// Phase 1: input projections. 4 WGs per timestep t (mq = batch quarter).
// ---------------------------------------------------------------------------
__global__ __launch_bounds__(256, 2) void gru_xpre(
    const float* __restrict__ X,
    const float* __restrict__ bz, const float* __restrict__ br, const float* __restrict__ bc,
    const unsigned short* __restrict__ wtab,
    unsigned short* __restrict__ Gx)
{
    __shared__ __align__(16) unsigned short x_lds[8192];   // 64 rows x 128 bf16, swizzled
    const int tid  = threadIdx.x;
    const int t    = blockIdx.x >> 2;
    const int mq   = blockIdx.x & 3;
    const int l    = tid & 63;
    const int v    = tid >> 6;
    const int quad = l >> 4;
    const int n    = l & 15;

    for (int i = tid; i < 1024; i += 256) {
        int lr = i >> 4, c = i & 15;
        const float* src = X + (size_t)((mq * 64 + lr) * SEQ + t) * NI + c * 8;
        f32x4 f0 = *(const f32x4*)(src);
        f32x4 f1 = *(const f32x4*)(src + 4);
        *(s16x8*)(&x_lds[lr * 128 + ((c ^ (lr & 15)) << 3)]) = pk8(f0, f1);
    }
    __syncthreads();

    const float* bp[3] = {bz, br, bc};
    const int rowA = n;
#pragma unroll 1
    for (int g = 0; g < 3; ++g) {
        s16x8 Bf[4][4];
        float bias[4];
#pragma unroll
        for (int tt = 0; tt < 4; ++tt) {
            bias[tt] = bp[g][v * 64 + tt * 16 + n];
#pragma unroll
            for (int kt = 0; kt < 4; ++kt)
                Bf[tt][kt] = *(const s16x8*)(wtab
                    + ((size_t)(v * 48 + g * 16 + tt * 4 + kt) * 64 + l) * 8);
        }

#pragma unroll 1
        for (int mtl = 0; mtl < 4; ++mtl) {
            const int mt = mq * 4 + mtl;
            f32x4 acc[4];
            const f32x4 z4 = {0.f, 0.f, 0.f, 0.f};
#pragma unroll
            for (int tt = 0; tt < 4; ++tt) acc[tt] = z4;

#pragma unroll
            for (int kt = 0; kt < 4; ++kt) {
                s16x8 a = *(const s16x8*)(&x_lds[(mtl * 16 + rowA) * 128
                                                 + (((kt * 4 + quad) ^ rowA) << 3)]);
#pragma unroll
                for (int tt = 0; tt < 4; ++tt)
                    acc[tt] = __builtin_amdgcn_mfma_f32_16x16x32_bf16(a, Bf[tt][kt], acc[tt], 0, 0, 0);
            }

#pragma unroll
            for (int tt = 0; tt < 4; ++tt) {
                float b = bias[tt];
                uint2 d;
                d.x = pkbf(acc[tt][0] + b, acc[tt][1] + b);
                d.y = pkbf(acc[tt][2] + b, acc[tt][3] + b);
                int chunk = (((t * 16 + mt) * 4 + v) * 3 + g) * 4 + tt;
                *(uint2*)((char*)Gx + (size_t)chunk * 512 + l * 8) = d;
            }
        }
    }
}

// ---------------------------------------------------------------------------
// Phase 1 (legacy gather variant, used when ws has room for Gx but not wtab)
// ---------------------------------------------------------------------------
__global__ __launch_bounds__(256, 1) void gru_xpre_gather(
    const float* __restrict__ X,
    const float* __restrict__ Wz, const float* __restrict__ bz,
    const float* __restrict__ Wr, const float* __restrict__ br,
    const float* __restrict__ Wc, const float* __restrict__ bc,
    unsigned short* __restrict__ Gx)
{
    __shared__ __align__(16) unsigned short x_lds[32768];
    const int tid  = threadIdx.x;
    const int t    = blockIdx.x;
    const int l    = tid & 63;
    const int v    = tid >> 6;
    const int quad = l >> 4;
    const int n    = l & 15;

    for (int i = tid; i < 4096; i += 256) {
        int row = i >> 4, c = i & 15;
        const float* src = X + (size_t)(row * SEQ + t) * NI + c * 8;
        f32x4 f0 = *(const f32x4*)(src);
        f32x4 f1 = *(const f32x4*)(src + 4);
        *(s16x8*)(&x_lds[row * 128 + ((c ^ (row & 15)) << 3)]) = pk8(f0, f1);
    }

    const float* Wp[3] = {Wz, Wr, Wc};
    const float* bp[3] = {bz, br, bc};
    s16x8 Bf[3][4][4];
    float bias[3][4];
#pragma unroll
    for (int g = 0; g < 3; ++g) {
#pragma unroll
        for (int tt = 0; tt < 4; ++tt) {
            int j = v * 64 + tt * 16 + n;
            bias[g][tt] = bp[g][j];
#pragma unroll
            for (int kt = 0; kt < 4; ++kt) {
                const float* src = Wp[g] + j * WROW + 256 + kt * 32 + quad * 8;
                f32x4 f0 = *(const f32x4*)(src);
                f32x4 f1 = *(const f32x4*)(src + 4);
                Bf[g][tt][kt] = pk8(f0, f1);
            }
        }
    }
    __syncthreads();

    const int rowA = l & 15;
#pragma unroll 1
    for (int mt = 0; mt < 16; ++mt) {
        f32x4 acc[3][4];
        f32x4 z4 = {0.f, 0.f, 0.f, 0.f};
#pragma unroll
        for (int g = 0; g < 3; ++g)
#pragma unroll
            for (int tt = 0; tt < 4; ++tt) acc[g][tt] = z4;

#pragma unroll
        for (int kt = 0; kt < 4; ++kt) {
            int row = mt * 16 + rowA;
            s16x8 a = *(const s16x8*)(&x_lds[row * 128 + (((kt * 4 + quad) ^ rowA) << 3)]);
#pragma unroll
            for (int g = 0; g < 3; ++g)
#pragma unroll
                for (int tt = 0; tt < 4; ++tt)
                    acc[g][tt] = __builtin_amdgcn_mfma_f32_16x16x32_bf16(a, Bf[g][tt][kt], acc[g][tt], 0, 0, 0);
        }

#pragma unroll
        for (int g = 0; g < 3; ++g)
#pragma unroll
            for (int tt = 0; tt < 4; ++tt) {
                float b = bias[g][tt];
                uint2 d;
                d.x = pkbf(acc[g][tt][0] + b, acc[g][tt][1] + b);
                d.y = pkbf(acc[g][tt][2] + b, acc[g][tt][3] + b);
                int chunk = (((t * 16 + mt) * 4 + v) * 3 + g) * 4 + tt;
                *(uint2*)((char*)Gx + (size_t)chunk * 512 + l * 8) = d;
            }
    }
}

// ---------------------------------------------------------------------------
// Phase 2: persistent recurrence. 16 WGs x 512 thr (8 waves, 2 waves/SIMD).
// ---------------------------------------------------------------------------
__global__ __launch_bounds__(512, 2) void gru_seq(
    const float* __restrict__ Wz, const float* __restrict__ Wr, const float* __restrict__ Wc,
    const unsigned short* __restrict__ Gx,
    float* __restrict__ out)
{
    __shared__ __align__(16) unsigned short wc_lds[32768];  // 64 frags x 64 lanes x 16 B
    __shared__ __align__(16) unsigned short h_lds[16][HPAD];
    __shared__ __align__(16) unsigned short rh_lds[16][HPAD];

    const int tid  = threadIdx.x;
    const int wg   = blockIdx.x;
    const int l    = tid & 63;
    const int w    = tid >> 6;       // wave 0..7
    const int quad = l >> 4;
    const int n    = l & 15;
    const int rowA = n;

    // resident Wz/Wr frags: Wf[g][tt][kt], j = w*32 + tt*16 + n, k = kt*32 + quad*8
    const float* Wp2[2] = {Wz, Wr};
    s16x8 Wf[2][2][8];
#pragma unroll
    for (int g = 0; g < 2; ++g)
#pragma unroll
        for (int tt = 0; tt < 2; ++tt)
#pragma unroll
            for (int kt = 0; kt < 8; ++kt) {
                int j = w * 32 + tt * 16 + n;
                const float* src = Wp2[g] + j * WROW + kt * 32 + quad * 8;
                f32x4 f0 = *(const f32x4*)(src);
                f32x4 f1 = *(const f32x4*)(src + 4);
                Wf[g][tt][kt] = pk8(f0, f1);
            }

    // resident Wc frags for kt 0..3 (same j/k mapping as Wf)
    s16x8 Wcr[2][4];
#pragma unroll
    for (int tt = 0; tt < 2; ++tt)
#pragma unroll
        for (int kt = 0; kt < 4; ++kt) {
            int j = w * 32 + tt * 16 + n;
            const float* src = Wc + j * WROW + kt * 32 + quad * 8;
            f32x4 f0 = *(const f32x4*)(src);
            f32x4 f1 = *(const f32x4*)(src + 4);
            Wcr[tt][kt] = pk8(f0, f1);
        }

    // build Wc frag table in LDS for kt 4..7: frag = jb*4 + (kt-4) (jb in [0,16)),
    // 1 KB each, lane ln holds B[k = kt*32 + (ln>>4)*8 .. +7][j = jb*16 + (ln&15)]
    for (int idx = tid; idx < 4096; idx += 512) {
        int fr = idx >> 6, ln = idx & 63;
        int jb = fr >> 2, ktm = fr & 3;
        int j = jb * 16 + (ln & 15);
        int k = (ktm + 4) * 32 + (ln >> 4) * 8;
        const float* src = Wc + j * WROW + k;
        f32x4 f0 = *(const f32x4*)(src);
        f32x4 f1 = *(const f32x4*)(src + 4);
        *(s16x8*)(&wc_lds[idx * 8]) = pk8(f0, f1);
    }

    // zero h state
    {
        unsigned short* hz = &h_lds[0][0];
        for (int i = tid; i < 16 * HPAD; i += 512) hz[i] = 0;
    }
    float hreg[2][4];
#pragma unroll
    for (int tt = 0; tt < 2; ++tt)
#pragma unroll
        for (int r = 0; r < 4; ++r) hreg[tt][r] = 0.0f;
    __syncthreads();

    // Gx addressing: chunk = ((t*16+wg)*4 + (w>>1))*12 + g*4 + (w&1)*2 + tt
    const char* gxbase = (const char*)Gx
        + (size_t)(((wg * 4 + (w >> 1)) * 12 + (w & 1) * 2) * 512) + l * 8;
    float* outp = out + (size_t)(wg * 16 + quad * 4) * 256 + w * 32 + n;
    const f32x4 z4 = {0.f, 0.f, 0.f, 0.f};

    // preload Gx for t=0
    uint2 ga[6];
#pragma unroll
    for (int i = 0; i < 6; ++i)
        ga[i] = *(const uint2*)(gxbase + (i >> 1) * 2048 + (i & 1) * 512);

#pragma unroll 1
    for (int t = 0; t < SEQ; ++t) {
        const char* gbn = gxbase + (size_t)(t + 1 < SEQ ? t + 1 : t) * 393216;

        // z/r MFMA
        f32x4 accZ[2], accR[2];
#pragma unroll
        for (int tt = 0; tt < 2; ++tt) { accZ[tt] = z4; accR[tt] = z4; }
#pragma unroll
        for (int kt = 0; kt < 8; ++kt) {
            s16x8 a = *(const s16x8*)(&h_lds[rowA][kt * 32 + quad * 8]);
#pragma unroll
            for (int tt = 0; tt < 2; ++tt) {
                accZ[tt] = __builtin_amdgcn_mfma_f32_16x16x32_bf16(a, Wf[0][tt][kt], accZ[tt], 0, 0, 0);
                accR[tt] = __builtin_amdgcn_mfma_f32_16x16x32_bf16(a, Wf[1][tt][kt], accR[tt], 0, 0, 0);
            }
        }

        // epilogue 1: extract z/r Gx, reload ga[0..3] (t+1), prefetch ALL wc kt4..7
        // frags into regs (issues on e1's LDS slack, completes at bar1's lgkmcnt(0)),
        // compute z, r, write r*h. Phase B then reads only the 64 rh A-frags.
        float zs[2][4];
        s16x8 Wcp[2][4];
        {
            float gzf[2][4], grf[2][4];
#pragma unroll
            for (int tt = 0; tt < 2; ++tt) {
                uint2 gz = ga[tt], gr = ga[2 + tt];
                gzf[tt][0] = bf2f((unsigned short)(gz.x & 0xffffu));
                gzf[tt][1] = bf2f((unsigned short)(gz.x >> 16));
                gzf[tt][2] = bf2f((unsigned short)(gz.y & 0xffffu));
                gzf[tt][3] = bf2f((unsigned short)(gz.y >> 16));
                grf[tt][0] = bf2f((unsigned short)(gr.x & 0xffffu));
                grf[tt][1] = bf2f((unsigned short)(gr.x >> 16));
                grf[tt][2] = bf2f((unsigned short)(gr.y & 0xffffu));
                grf[tt][3] = bf2f((unsigned short)(gr.y >> 16));
            }
#pragma unroll
            for (int i = 0; i < 4; ++i)
                ga[i] = *(const uint2*)(gbn + (i >> 1) * 2048 + (i & 1) * 512);
#pragma unroll
            for (int tt = 0; tt < 2; ++tt)
#pragma unroll
                for (int k2 = 0; k2 < 4; ++k2)
                    Wcp[tt][k2] = *(const s16x8*)(&wc_lds[(((w * 2 + tt) * 4 + k2) * 64 + l) * 8]);
#pragma unroll
            for (int tt = 0; tt < 2; ++tt) {
                float rh[4];
#pragma unroll
                for (int r = 0; r < 4; ++r) {
                    float zv = sigm(accZ[tt][r] + gzf[tt][r]);
                    float rv = sigm(accR[tt][r] + grf[tt][r]);
                    zs[tt][r] = zv;
                    rh[r] = rv * hreg[tt][r];
                }
                unsigned pa = pkbf(rh[0], rh[1]);
                unsigned pb = pkbf(rh[2], rh[3]);
                const int col = w * 32 + tt * 16 + n;
                rh_lds[quad * 4 + 0][col] = (unsigned short)pa;
                rh_lds[quad * 4 + 1][col] = (unsigned short)(pa >> 16);
                rh_lds[quad * 4 + 2][col] = (unsigned short)pb;
                rh_lds[quad * 4 + 3][col] = (unsigned short)(pb >> 16);
            }
        }
        lds_barrier();   // r*h published; h_lds reads + Wcp prefetch complete

        // candidate MFMA (Wc kt0..3 resident regs, kt4..7 prefetched regs)
        f32x4 accC[2];
#pragma unroll
        for (int tt = 0; tt < 2; ++tt) accC[tt] = z4;
#pragma unroll
        for (int kt = 0; kt < 8; ++kt) {
            s16x8 a = *(const s16x8*)(&rh_lds[rowA][kt * 32 + quad * 8]);
#pragma unroll
            for (int tt = 0; tt < 2; ++tt) {
                s16x8 b = (kt < 4) ? Wcr[tt][kt] : Wcp[tt][kt - 4];
                accC[tt] = __builtin_amdgcn_mfma_f32_16x16x32_bf16(a, b, accC[tt], 0, 0, 0);
            }
        }

        // epilogue 2: extract c Gx, reload ga[4..5] for t+1, candidate, h update, stores
        {
            float gcf[2][4];
#pragma unroll
            for (int tt = 0; tt < 2; ++tt) {
                uint2 gc = ga[4 + tt];
                gcf[tt][0] = bf2f((unsigned short)(gc.x & 0xffffu));
                gcf[tt][1] = bf2f((unsigned short)(gc.x >> 16));
                gcf[tt][2] = bf2f((unsigned short)(gc.y & 0xffffu));
                gcf[tt][3] = bf2f((unsigned short)(gc.y >> 16));
            }
#pragma unroll
            for (int i = 4; i < 6; ++i)
                ga[i] = *(const uint2*)(gbn + 4096 + (i & 1) * 512);
            float* op = outp + (size_t)t * 65536;
#pragma unroll
            for (int tt = 0; tt < 2; ++tt) {
                float hn4[4];
#pragma unroll
                for (int r = 0; r < 4; ++r) {
                    float cv = tanh_(accC[tt][r] + gcf[tt][r]);
                    float h  = hreg[tt][r];
                    float hn = fmaf(zs[tt][r], cv - h, h);
                    hreg[tt][r] = hn;
                    hn4[r] = hn;
                }
                unsigned pa = pkbf(hn4[0], hn4[1]);
                unsigned pb = pkbf(hn4[2], hn4[3]);
                const int col = w * 32 + tt * 16 + n;
                h_lds[quad * 4 + 0][col] = (unsigned short)pa;
                h_lds[quad * 4 + 1][col] = (unsigned short)(pa >> 16);
                h_lds[quad * 4 + 2][col] = (unsigned short)pb;
                h_lds[quad * 4 + 3][col] = (unsigned short)(pb >> 16);
#pragma unroll
                for (int r = 0; r < 4; ++r)
                    op[r * 256 + tt * 16] = hn4[r];
            }
        }
        lds_barrier();   // h published for next step
    }
}

// ---------------------------------------------------------------------------
// Fallback (only if ws too small): naive fp32, correct but slow.
// ---------------------------------------------------------------------------
__global__ __launch_bounds__(1024, 1) void gru_fallback(
    const float* __restrict__ X,
    const float* __restrict__ Wz, const float* __restrict__ bz,
    const float* __restrict__ Wr, const float* __restrict__ br,
    const float* __restrict__ Wc, const float* __restrict__ bc,
    float* __restrict__ out)
{
    __shared__ float h_s[16][257];
    __shared__ float rh_s[16][257];
    __shared__ float x_s[16][128];
    const int tid = threadIdx.x;
    const int wg = blockIdx.x, b0 = wg * 16;
    const int m = tid >> 6, jq = tid & 63;
    for (int i = tid; i < 16 * 257; i += 1024) (&h_s[0][0])[i] = 0.0f;
    __syncthreads();
    for (int t = 0; t < SEQ; ++t) {
        for (int i = tid; i < 2048; i += 1024) {
            int row = i >> 7, k = i & 127;
            x_s[row][k] = X[(size_t)((b0 + row) * SEQ + t) * NI + k];
        }
        __syncthreads();
        float zv[4];
        for (int jj = 0; jj < 4; ++jj) {
            int j = jj * 64 + jq;
            float az = bz[j], ar = br[j];
            for (int k = 0; k < 256; ++k) { float h = h_s[m][k]; az += h * Wz[j * WROW + k]; ar += h * Wr[j * WROW + k]; }
            for (int k = 0; k < 128; ++k) { float x = x_s[m][k]; az += x * Wz[j * WROW + 256 + k]; ar += x * Wr[j * WROW + 256 + k]; }
            float z = sigm(az), r = sigm(ar);
            zv[jj] = z;
            rh_s[m][j] = r * h_s[m][j];
        }
        __syncthreads();
        float hn[4];
        for (int jj = 0; jj < 4; ++jj) {
            int j = jj * 64 + jq;
            float ac = bc[j];
            for (int k = 0; k < 256; ++k) ac += rh_s[m][k] * Wc[j * WROW + k];
            for (int k = 0; k < 128; ++k) ac += x_s[m][k] * Wc[j * WROW + 256 + k];
            float c = tanh_(ac);
            float h = h_s[m][j];
            hn[jj] = fmaf(zv[jj], c - h, h);
        }
        __syncthreads();
        for (int jj = 0; jj < 4; ++jj) {
            int j = jj * 64 + jq;
            h_s[m][j] = hn[jj];
            out[(size_t)(t * 256 + b0 + m) * 256 + j] = hn[jj];
        }
        __syncthreads();
    }
}

extern "C" void kernel_launch(void* const* d_in, const int* in_sizes, int n_in,
                              void* d_out, int out_size, void* d_ws, size_t ws_size,
                              hipStream_t stream) {
    const float* X  = (const float*)d_in[0];
    const float* Wz = (const float*)d_in[1];
    const float* bz = (const float*)d_in[2];
    const float* Wr = (const float*)d_in[3];
    const float* br = (const float*)d_in[4];
    const float* Wc = (const float*)d_in[5];
    const float* bc = (const float*)d_in[6];
    float* out = (float*)d_out;

    if (ws_size >= GX_BYTES + WTAB_BYTES) {
        unsigned short* Gx   = (unsigned short*)d_ws;
        unsigned short* wtab = (unsigned short*)((char*)d_ws + GX_BYTES);
        gru_wprep<<<48, 256, 0, stream>>>(Wz, Wr, Wc, wtab);
        gru_xpre<<<2048, 256, 0, stream>>>(X, bz, br, bc, wtab, Gx);
        gru_seq<<<16, 512, 0, stream>>>(Wz, Wr, Wc, Gx, out);
    } else if (ws_size >= GX_BYTES) {
        unsigned short* Gx = (unsigned short*)d_ws;
        gru_xpre_gather<<<512, 256, 0, stream>>>(X, Wz, bz, Wr, br, Wc, bc, Gx);
        gru_seq<<<16, 512, 0, stream>>>(Wz, Wr, Wc, Gx, out);
    } else {
        gru_fallback<<<16, 1024, 0, stream>>>(X, Wz, bz, Wr, br, Wc, bc, out);
    }
}